// Round 2
// baseline (1471.985 us; speedup 1.0000x reference)
//
#include <hip/hip_runtime.h>
#include <math.h>

#define NH   16
#define NKV  4
#define HD   128
#define BSZ  4
#define TLEN 2048
#define CDIM 2048
#define MROWS (BSZ*TLEN)   // 8192

typedef short bf16x8 __attribute__((ext_vector_type(8)));
typedef float f32x4  __attribute__((ext_vector_type(4)));
typedef int   int4v  __attribute__((ext_vector_type(4)));

__device__ inline float bf2f(unsigned short h) {
  union { unsigned u; float f; } x; x.u = ((unsigned)h) << 16; return x.f;
}
__device__ inline unsigned short f2bf(float f) {
  union { float f; unsigned u; } x; x.f = f;
  unsigned u = x.u;
  return (unsigned short)((u + 0x7FFFu + ((u >> 16) & 1u)) >> 16);
}

// ---------------------------------------------------------------------------
// Dtype detector. Reads the EVEN shorts of w_proj. If the buffer holds bf16,
// every even short is a bf16 of ~N(0, 0.022) -> exponent field in ~[100,126].
// If it holds fp32, even shorts are low-mantissa garbage -> uniform exponents,
// only ~20% land in the sane window. flag=1 => bf16 storage.
// ---------------------------------------------------------------------------
__global__ void detect_kernel(const void* __restrict__ wproj, int* __restrict__ flag) {
  __shared__ int cnt;
  if (threadIdx.x == 0) cnt = 0;
  __syncthreads();
  const unsigned short* s = (const unsigned short*)wproj;
  unsigned short v = s[2 * threadIdx.x];          // 256 even shorts
  int e = (v >> 7) & 0xFF;
  if (e >= 90 && e <= 141) atomicAdd(&cnt, 1);
  __syncthreads();
  if (threadIdx.x == 0) *flag = (cnt >= 192) ? 1 : 0;
}

// Stage 8 contiguous elements (16B of bf16) into LDS; converts from fp32 if needed.
__device__ inline void stage8(short* dst, const void* src, size_t eoff, int isbf) {
  if (isbf) {
    *(int4v*)dst = *(const int4v*)((const short*)src + eoff);
  } else {
    const f32x4* f = (const f32x4*)((const float*)src + eoff);
    f32x4 a = f[0], b = f[1];
    short t[8];
    t[0] = (short)f2bf(a[0]); t[1] = (short)f2bf(a[1]);
    t[2] = (short)f2bf(a[2]); t[3] = (short)f2bf(a[3]);
    t[4] = (short)f2bf(b[0]); t[5] = (short)f2bf(b[1]);
    t[6] = (short)f2bf(b[2]); t[7] = (short)f2bf(b[3]);
    *(int4v*)dst = *(int4v*)t;
  }
}

// ---------------------------------------------------------------------------
// GEMM  C[m,n] = sum_k A[m,k] * W[n,k]   (fp32 accum, bf16 MFMA)
// 128x128 tile, BK=32, 256 threads (4 waves, each 4x4 16x16 mfma tiles).
// MODE 0: A=x, W=w_attn -> scatter q[B,16,T,128], k[B,4,T,128], vT[B,4,128,T]
// MODE 1: A=yb (always bf16), W=w_proj -> store to o0 (bf16) or o0f (fp32)
// ---------------------------------------------------------------------------
template<int MODE>
__global__ __launch_bounds__(256) void gemm_bt(
    const void* __restrict__ A, const void* __restrict__ W,
    short* __restrict__ o0, short* __restrict__ o1, short* __restrict__ o2,
    float* __restrict__ o0f, const int* __restrict__ flagp)
{
  __shared__ short As[128*32];
  __shared__ short Bs[128*32];
  const int fl  = *flagp;                 // 1 = bf16 storage
  const int aBf = (MODE == 1) ? 1 : fl;
  const int wBf = fl;
  const int tid  = threadIdx.x;
  const int wave = tid >> 6;
  const int lane = tid & 63;
  const int cl   = lane & 15;
  const int quad = lane >> 4;
  const int m0 = blockIdx.y * 128;
  const int n0 = blockIdx.x * 128;
  const int rowS = tid >> 2;            // 0..63
  const int colS = (tid & 3) << 3;      // 0,8,16,24
  const int wr = (wave >> 1) * 64;
  const int wc = (wave & 1) * 64;
  const int K = CDIM;

  f32x4 acc[4][4];
#pragma unroll
  for (int i = 0; i < 4; i++)
#pragma unroll
    for (int j = 0; j < 4; j++) acc[i][j] = (f32x4){0.f, 0.f, 0.f, 0.f};

  for (int k0 = 0; k0 < K; k0 += 32) {
    stage8(&As[rowS*32 + colS],      A, (size_t)(m0+rowS)*K    + k0 + colS, aBf);
    stage8(&As[(rowS+64)*32 + colS], A, (size_t)(m0+rowS+64)*K + k0 + colS, aBf);
    stage8(&Bs[rowS*32 + colS],      W, (size_t)(n0+rowS)*K    + k0 + colS, wBf);
    stage8(&Bs[(rowS+64)*32 + colS], W, (size_t)(n0+rowS+64)*K + k0 + colS, wBf);
    __syncthreads();
    bf16x8 af[4], bfr[4];
#pragma unroll
    for (int i = 0; i < 4; i++) af[i]  = *(const bf16x8*)(&As[(wr + i*16 + cl)*32 + quad*8]);
#pragma unroll
    for (int j = 0; j < 4; j++) bfr[j] = *(const bf16x8*)(&Bs[(wc + j*16 + cl)*32 + quad*8]);
#pragma unroll
    for (int i = 0; i < 4; i++)
#pragma unroll
      for (int j = 0; j < 4; j++)
        acc[i][j] = __builtin_amdgcn_mfma_f32_16x16x32_bf16(af[i], bfr[j], acc[i][j], 0, 0, 0);
    __syncthreads();
  }

  // C/D layout (verified m89/m91): col = lane&15, row = quad*4 + reg.
#pragma unroll
  for (int i = 0; i < 4; i++) {
#pragma unroll
    for (int j = 0; j < 4; j++) {
#pragma unroll
      for (int r = 0; r < 4; r++) {
        const int gm = m0 + wr + i*16 + quad*4 + r;
        const int gn = n0 + wc + j*16 + cl;
        const float fv = acc[i][j][r];
        if (MODE == 1) {
          if (fl) o0[(size_t)gm * CDIM + gn] = (short)f2bf(fv);
          else    o0f[(size_t)gm * CDIM + gn] = fv;
        } else {
          const int b = gm >> 11;          // /TLEN
          const int t = gm & (TLEN - 1);
          const int head = gn >> 7;        // 0..23
          const int d = gn & (HD - 1);
          const unsigned short h = f2bf(fv);
          if (head < 16) {
            o0[(((size_t)(b*NH + head) * TLEN + t) << 7) + d] = (short)h;
          } else if (head < 20) {
            o1[(((size_t)(b*NKV + (head-16)) * TLEN + t) << 7) + d] = (short)h;
          } else {
            o2[(((size_t)(b*NKV + (head-20)) * HD + d) << 11) + t] = (short)h;  // vT[b][kv][d][t]
          }
        }
      }
    }
  }
}

// ---------------------------------------------------------------------------
// RoPE in place on q [B,16,T,128] and k [B,4,T,128]; interleaved pairs.
// planes: 0..63 = q (b*16+h), 64..79 = k (b*4+kv).
// ---------------------------------------------------------------------------
__global__ __launch_bounds__(256) void rope_kernel(short* __restrict__ qb,
                                                   short* __restrict__ kb)
{
  const int idx = blockIdx.x * 256 + threadIdx.x;   // exactly 80*2048*64 threads
  const int per_plane = TLEN * 64;
  const int plane = idx / per_plane;
  const int rem = idx - plane * per_plane;
  const int t = rem >> 6;
  const int i = rem & 63;
  short* base = (plane < 64) ? (qb + (size_t)plane * (TLEN*HD))
                             : (kb + (size_t)(plane - 64) * (TLEN*HD));
  const size_t off = (size_t)t * HD + 2*i;
  const float x1 = bf2f((unsigned short)base[off]);
  const float x2 = bf2f((unsigned short)base[off+1]);
  const float inv = __expf(-0.14391156847064198f * (float)i);  // 10000^(-2i/128)
  const float ang = (float)t * inv;
  float s, c;
  sincosf(ang, &s, &c);
  base[off]   = (short)f2bf(x1*c - x2*s);
  base[off+1] = (short)f2bf(x1*s + x2*c);
}

// ---------------------------------------------------------------------------
// Flash attention (causal). Block = 4 waves; wave w owns q-rows
// [q0+16w, q0+16w+16). K-tiles of 64. QK^T / PV via mfma 16x16x32.
//
// R2 change: __launch_bounds__(256, 2). R1 compiled to only 92 VGPRs, which
// forced the scheduler to re-serialize the kf[4][4]/vf[2][8] batched loads
// (192+ live regs requested, 92 granted). 2 blocks/CU raises the cap to 256
// VGPRs/wave; measured occupancy was already ~24% (~8 waves/CU) so the
// residency cap costs nothing. All 32 loads genuinely in flight now.
// ---------------------------------------------------------------------------
__global__ __launch_bounds__(256, 2) void attn_kernel(
    const short* __restrict__ qb, const short* __restrict__ kb,
    const short* __restrict__ vtb, short* __restrict__ yb)
{
  __shared__ short Plds[4][16][64];
  const int tid  = threadIdx.x;
  const int wave = tid >> 6;
  const int lane = tid & 63;
  const int cl   = lane & 15;
  const int quad = lane >> 4;
  const int bh = blockIdx.y;
  const int b = bh >> 4, h = bh & 15;
  const int kvh = h >> 2;

  const short* Qp = qb  + (size_t)(b*NH  + h)   * TLEN * HD;
  const short* Kp = kb  + (size_t)(b*NKV + kvh) * TLEN * HD;
  const short* Vp = vtb + (size_t)(b*NKV + kvh) * HD * TLEN;
  short* Pw = &Plds[wave][0][0];

  const float scale = 0.08838834764831845f;  // 1/sqrt(128)

#pragma unroll 1
  for (int pass = 0; pass < 2; ++pass) {
    const int qi = pass ? (TLEN/64 - 1 - (int)blockIdx.x) : (int)blockIdx.x;
    const int q0 = qi * 64;
    const int ntiles = qi + 1;

    bf16x8 qf[4];
    const int qrow = q0 + wave*16 + cl;
#pragma unroll
    for (int s = 0; s < 4; s++)
      qf[s] = *(const bf16x8*)(Qp + (size_t)qrow*HD + s*32 + quad*8);

    f32x4 O[8];
#pragma unroll
    for (int d = 0; d < 8; d++) O[d] = (f32x4){0.f, 0.f, 0.f, 0.f};
    float m_i[4], l_i[4];
#pragma unroll
    for (int r = 0; r < 4; r++) { m_i[r] = -1e9f; l_i[r] = 0.f; }

    for (int kt = 0; kt < ntiles; kt++) {
      const int k0 = kt * 64;

      // --- batched K fragment loads: 16 independent 16B loads in flight ---
      bf16x8 kf[4][4];
#pragma unroll
      for (int s = 0; s < 4; s++)
#pragma unroll
        for (int j = 0; j < 4; j++)
          kf[s][j] = *(const bf16x8*)(Kp + (size_t)(k0 + j*16 + cl)*HD + s*32 + quad*8);

      f32x4 S[4];
#pragma unroll
      for (int j = 0; j < 4; j++) S[j] = (f32x4){0.f, 0.f, 0.f, 0.f};
#pragma unroll
      for (int s = 0; s < 4; s++)
#pragma unroll
        for (int j = 0; j < 4; j++)
          S[j] = __builtin_amdgcn_mfma_f32_16x16x32_bf16(qf[s], kf[s][j], S[j], 0, 0, 0);

      // --- issue V loads NOW; latency hides under the softmax chain ---
      bf16x8 vf[2][8];
#pragma unroll
      for (int s2 = 0; s2 < 2; s2++)
#pragma unroll
        for (int d = 0; d < 8; d++)
          vf[s2][d] = *(const bf16x8*)(Vp + (size_t)(d*16 + cl)*TLEN + k0 + s2*32 + quad*8);

      // --- causal mask + scale ---
#pragma unroll
      for (int j = 0; j < 4; j++) {
        const int col = k0 + j*16 + cl;
#pragma unroll
        for (int r = 0; r < 4; r++) {
          const int row = q0 + wave*16 + quad*4 + r;
          const float sv = S[j][r] * scale;
          S[j][r] = (col <= row) ? sv : -1e9f;
        }
      }

      // --- online softmax (row r lives on lanes with same quad,r; 16 cols/lane-group) ---
      float alpha[4];
#pragma unroll
      for (int r = 0; r < 4; r++) {
        float mx = fmaxf(fmaxf(S[0][r], S[1][r]), fmaxf(S[2][r], S[3][r]));
#pragma unroll
        for (int off = 1; off < 16; off <<= 1) mx = fmaxf(mx, __shfl_xor(mx, off));
        const float mnew = fmaxf(m_i[r], mx);
        alpha[r] = __expf(m_i[r] - mnew);
        float rs = 0.f;
#pragma unroll
        for (int j = 0; j < 4; j++) {
          const float p = __expf(S[j][r] - mnew);
          S[j][r] = p;
          rs += p;
        }
#pragma unroll
        for (int off = 1; off < 16; off <<= 1) rs += __shfl_xor(rs, off);
        l_i[r] = l_i[r] * alpha[r] + rs;
        m_i[r] = mnew;
      }
#pragma unroll
      for (int d = 0; d < 8; d++)
#pragma unroll
        for (int r = 0; r < 4; r++) O[d][r] *= alpha[r];

      // --- P -> LDS (wave-private slice, XOR-swizzled; no barrier needed) ---
#pragma unroll
      for (int j = 0; j < 4; j++)
#pragma unroll
        for (int r = 0; r < 4; r++) {
          const int row = quad*4 + r;
          int idx = row*64 + j*16 + cl;
          idx ^= (row & 7) << 3;
          Pw[idx] = (short)f2bf(S[j][r]);
        }

      // --- PV: P (A-operand) from LDS, V from the prefetched registers ---
#pragma unroll
      for (int s2 = 0; s2 < 2; s2++) {
        int idx = cl*64 + s2*32 + quad*8;
        idx ^= (cl & 7) << 3;
        bf16x8 pf = *(const bf16x8*)(&Pw[idx]);
#pragma unroll
        for (int d = 0; d < 8; d++)
          O[d] = __builtin_amdgcn_mfma_f32_16x16x32_bf16(pf, vf[s2][d], O[d], 0, 0, 0);
      }
    }

#pragma unroll
    for (int d = 0; d < 8; d++) {
#pragma unroll
      for (int r = 0; r < 4; r++) {
        const int t = q0 + wave*16 + quad*4 + r;
        const float v = O[d][r] / l_i[r];
        yb[(size_t)(b*TLEN + t) * CDIM + h*HD + d*16 + cl] = (short)f2bf(v);
      }
    }
  }
}

// ---------------------------------------------------------------------------
extern "C" void kernel_launch(void* const* d_in, const int* in_sizes, int n_in,
                              void* d_out, int out_size, void* d_ws, size_t ws_size,
                              hipStream_t stream)
{
  const void* x      = d_in[0];   // [B,T,C]
  const void* w_attn = d_in[1];   // [3072,2048]
  const void* w_proj = d_in[2];   // [2048,2048]

  char* ws = (char*)d_ws;
  int*   flag = (int*)ws;
  short* qb  = (short*)(ws + (size_t) 1*1024*1024);   // 32 MB: q  [B,16,T,128]
  short* kb  = (short*)(ws + (size_t)33*1024*1024);   //  8 MB: k  [B,4,T,128]
  short* vtb = (short*)(ws + (size_t)41*1024*1024);   //  8 MB: vT [B,4,128,T]
  short* yb  = (short*)(ws + (size_t)49*1024*1024);   // 32 MB: y  [B,T,C]

  dim3 blk(256);
  detect_kernel<<<1, blk, 0, stream>>>(w_proj, flag);
  gemm_bt<0><<<dim3(3072/128, MROWS/128), blk, 0, stream>>>(x, w_attn, qb, kb, vtb, nullptr, flag);
  rope_kernel<<<dim3((80*TLEN*64)/256), blk, 0, stream>>>(qb, kb);
  attn_kernel<<<dim3(TLEN/128, BSZ*NH), blk, 0, stream>>>(qb, kb, vtb, yb);
  gemm_bt<1><<<dim3(CDIM/128, MROWS/128), blk, 0, stream>>>(yb, w_proj, (short*)d_out,
                                                            nullptr, nullptr, (float*)d_out, flag);
}

// Round 4
// 898.355 us; speedup vs baseline: 1.6385x; 1.6385x over previous
//
#include <hip/hip_runtime.h>
#include <math.h>

#define NH   16
#define NKV  4
#define HD   128
#define BSZ  4
#define TLEN 2048
#define CDIM 2048
#define MROWS (BSZ*TLEN)   // 8192

typedef short bf16x8 __attribute__((ext_vector_type(8)));
typedef float f32x4  __attribute__((ext_vector_type(4)));
typedef int   int4v  __attribute__((ext_vector_type(4)));

__device__ inline float bf2f(unsigned short h) {
  union { unsigned u; float f; } x; x.u = ((unsigned)h) << 16; return x.f;
}
__device__ inline unsigned short f2bf(float f) {
  union { float f; unsigned u; } x; x.f = f;
  unsigned u = x.u;
  return (unsigned short)((u + 0x7FFFu + ((u >> 16) & 1u)) >> 16);
}

// Async global->LDS DMA, 16B per lane. LDS dest = wave-uniform base + lane*16.
__device__ inline void gload_lds16(const void* g, void* l) {
  __builtin_amdgcn_global_load_lds((const __attribute__((address_space(1))) void*)g,
                                   (__attribute__((address_space(3))) void*)l, 16, 0, 0);
}

// ---------------------------------------------------------------------------
// Dtype detector (unchanged): flag=1 => inputs are packed bf16.
// ---------------------------------------------------------------------------
__global__ void detect_kernel(const void* __restrict__ wproj, int* __restrict__ flag) {
  __shared__ int cnt;
  if (threadIdx.x == 0) cnt = 0;
  __syncthreads();
  const unsigned short* s = (const unsigned short*)wproj;
  unsigned short v = s[2 * threadIdx.x];          // 256 even shorts
  int e = (v >> 7) & 0xFF;
  if (e >= 90 && e <= 141) atomicAdd(&cnt, 1);
  __syncthreads();
  if (threadIdx.x == 0) *flag = (cnt >= 192) ? 1 : 0;
}

// Produce 8 contiguous bf16 from source (bf16 copy or fp32 convert).
__device__ inline void stage8(short* dst, const void* src, size_t eoff, int isbf) {
  if (isbf) {
    *(int4v*)dst = *(const int4v*)((const short*)src + eoff);
  } else {
    const f32x4* f = (const f32x4*)((const float*)src + eoff);
    f32x4 a = f[0], b = f[1];
    __align__(16) short t[8];
    t[0] = (short)f2bf(a[0]); t[1] = (short)f2bf(a[1]);
    t[2] = (short)f2bf(a[2]); t[3] = (short)f2bf(a[3]);
    t[4] = (short)f2bf(b[0]); t[5] = (short)f2bf(b[1]);
    t[6] = (short)f2bf(b[2]); t[7] = (short)f2bf(b[3]);
    *(int4v*)dst = *(int4v*)t;
  }
}

// ---------------------------------------------------------------------------
// One-shot convert/copy to packed bf16. 8 elems/thread, fully coalesced.
// Replaces per-tile VALU conversion that gemm re-did 24-64x per element.
// ---------------------------------------------------------------------------
__global__ __launch_bounds__(256) void cvt_kernel(const void* __restrict__ src,
                                                  short* __restrict__ dst,
                                                  int n8, const int* __restrict__ flagp)
{
  const int fl = *flagp;
  const int i = blockIdx.x * 256 + threadIdx.x;
  if (i >= n8) return;
  __align__(16) short t[8];
  stage8(t, src, (size_t)i * 8, fl);
  *(int4v*)(dst + (size_t)i * 8) = *(int4v*)t;
}

// ---------------------------------------------------------------------------
// GEMM  C[m,n] = sum_k A[m,k] * W[n,k]   (bf16 inputs, fp32 accum)
// m97 structure: 128x128 tile, BK=32, 256 threads (4 waves, 4x4 16x16 frags),
// global_load_lds dwordx4 staging (zero VGPR cost), 2-barrier K-loop.
// Staging map: lane writes LDS short idx rq*32+cq where rq=tid/4, cq=(tid&3)*8
// == exactly the [row][32-col] layout the fragment reads use.
// MODE 0: scatter q[B,16,T,128], k[B,4,T,128], vT[B,4,128,T]
// MODE 1: store to o0 (bf16) or o0f (fp32) per flag
// ---------------------------------------------------------------------------
template<int MODE>
__global__ __launch_bounds__(256) void gemm_bt(
    const short* __restrict__ A, const short* __restrict__ W,
    short* __restrict__ o0, short* __restrict__ o1, short* __restrict__ o2,
    float* __restrict__ o0f, const int* __restrict__ flagp)
{
  __shared__ __align__(16) short As[128*32];
  __shared__ __align__(16) short Bs[128*32];
  const int fl = *flagp;
  const int tid  = threadIdx.x;
  const int wave = tid >> 6;
  const int lane = tid & 63;
  const int cl   = lane & 15;
  const int quad = lane >> 4;
  const int m0 = blockIdx.y * 128;
  const int n0 = blockIdx.x * 128;
  const int wr = (wave >> 1) * 64;
  const int wc = (wave & 1) * 64;
  const int K = CDIM;
  const int rq = tid >> 2;             // 0..63
  const int cq = (tid & 3) << 3;       // 0,8,16,24
  const short* Ap = A + (size_t)(m0 + rq) * K + cq;
  const short* Wp = W + (size_t)(n0 + rq) * K + cq;
  short* AsW = As + wave * 512;        // + lane*8 shorts appended by HW
  short* BsW = Bs + wave * 512;
  const size_t rowskip = (size_t)64 * K;

  f32x4 acc[4][4];
#pragma unroll
  for (int i = 0; i < 4; i++)
#pragma unroll
    for (int j = 0; j < 4; j++) acc[i][j] = (f32x4){0.f, 0.f, 0.f, 0.f};

  for (int k0 = 0; k0 < K; k0 += 32) {
    gload_lds16(Ap + k0,           AsW);
    gload_lds16(Ap + k0 + rowskip, AsW + 2048);
    gload_lds16(Wp + k0,           BsW);
    gload_lds16(Wp + k0 + rowskip, BsW + 2048);
    __syncthreads();   // drains vmcnt (LDS-DMA) + lgkmcnt
    bf16x8 af[4], bfr[4];
#pragma unroll
    for (int i = 0; i < 4; i++) af[i]  = *(const bf16x8*)(&As[(wr + i*16 + cl)*32 + quad*8]);
#pragma unroll
    for (int j = 0; j < 4; j++) bfr[j] = *(const bf16x8*)(&Bs[(wc + j*16 + cl)*32 + quad*8]);
#pragma unroll
    for (int i = 0; i < 4; i++)
#pragma unroll
      for (int j = 0; j < 4; j++)
        acc[i][j] = __builtin_amdgcn_mfma_f32_16x16x32_bf16(af[i], bfr[j], acc[i][j], 0, 0, 0);
    __syncthreads();   // protect LDS from next-iter staging
  }

  // C/D layout (verified m89/m91): col = lane&15, row = quad*4 + reg.
#pragma unroll
  for (int i = 0; i < 4; i++) {
#pragma unroll
    for (int j = 0; j < 4; j++) {
#pragma unroll
      for (int r = 0; r < 4; r++) {
        const int gm = m0 + wr + i*16 + quad*4 + r;
        const int gn = n0 + wc + j*16 + cl;
        const float fv = acc[i][j][r];
        if (MODE == 1) {
          if (fl) o0[(size_t)gm * CDIM + gn] = (short)f2bf(fv);
          else    o0f[(size_t)gm * CDIM + gn] = fv;
        } else {
          const int b = gm >> 11;          // /TLEN
          const int t = gm & (TLEN - 1);
          const int head = gn >> 7;        // 0..23
          const int d = gn & (HD - 1);
          const unsigned short h = f2bf(fv);
          if (head < 16) {
            o0[(((size_t)(b*NH + head) * TLEN + t) << 7) + d] = (short)h;
          } else if (head < 20) {
            o1[(((size_t)(b*NKV + (head-16)) * TLEN + t) << 7) + d] = (short)h;
          } else {
            o2[(((size_t)(b*NKV + (head-20)) * HD + d) << 11) + t] = (short)h;  // vT[b][kv][d][t]
          }
        }
      }
    }
  }
}

// ---------------------------------------------------------------------------
// RoPE in place on q [B,16,T,128] and k [B,4,T,128]; interleaved pairs.
// ---------------------------------------------------------------------------
__global__ __launch_bounds__(256) void rope_kernel(short* __restrict__ qb,
                                                   short* __restrict__ kb)
{
  const int idx = blockIdx.x * 256 + threadIdx.x;   // exactly 80*2048*64 threads
  const int per_plane = TLEN * 64;
  const int plane = idx / per_plane;
  const int rem = idx - plane * per_plane;
  const int t = rem >> 6;
  const int i = rem & 63;
  short* base = (plane < 64) ? (qb + (size_t)plane * (TLEN*HD))
                             : (kb + (size_t)(plane - 64) * (TLEN*HD));
  const size_t off = (size_t)t * HD + 2*i;
  const float x1 = bf2f((unsigned short)base[off]);
  const float x2 = bf2f((unsigned short)base[off+1]);
  const float inv = __expf(-0.14391156847064198f * (float)i);  // 10000^(-2i/128)
  const float ang = (float)t * inv;
  float s, c;
  sincosf(ang, &s, &c);
  base[off]   = (short)f2bf(x1*c - x2*s);
  base[off+1] = (short)f2bf(x1*s + x2*c);
}

// ---------------------------------------------------------------------------
// Flash attention (causal) — exact R1 form (measured 502 us; R2's
// launch_bounds(256,2) regressed to 744 us / 76 VGPR, reverted).
// ---------------------------------------------------------------------------
__global__ __launch_bounds__(256) void attn_kernel(
    const short* __restrict__ qb, const short* __restrict__ kb,
    const short* __restrict__ vtb, short* __restrict__ yb)
{
  __shared__ short Plds[4][16][64];
  const int tid  = threadIdx.x;
  const int wave = tid >> 6;
  const int lane = tid & 63;
  const int cl   = lane & 15;
  const int quad = lane >> 4;
  const int bh = blockIdx.y;
  const int b = bh >> 4, h = bh & 15;
  const int kvh = h >> 2;

  const short* Qp = qb  + (size_t)(b*NH  + h)   * TLEN * HD;
  const short* Kp = kb  + (size_t)(b*NKV + kvh) * TLEN * HD;
  const short* Vp = vtb + (size_t)(b*NKV + kvh) * HD * TLEN;
  short* Pw = &Plds[wave][0][0];

  const float scale = 0.08838834764831845f;  // 1/sqrt(128)

#pragma unroll 1
  for (int pass = 0; pass < 2; ++pass) {
    const int qi = pass ? (TLEN/64 - 1 - (int)blockIdx.x) : (int)blockIdx.x;
    const int q0 = qi * 64;
    const int ntiles = qi + 1;

    bf16x8 qf[4];
    const int qrow = q0 + wave*16 + cl;
#pragma unroll
    for (int s = 0; s < 4; s++)
      qf[s] = *(const bf16x8*)(Qp + (size_t)qrow*HD + s*32 + quad*8);

    f32x4 O[8];
#pragma unroll
    for (int d = 0; d < 8; d++) O[d] = (f32x4){0.f, 0.f, 0.f, 0.f};
    float m_i[4], l_i[4];
#pragma unroll
    for (int r = 0; r < 4; r++) { m_i[r] = -1e9f; l_i[r] = 0.f; }

    for (int kt = 0; kt < ntiles; kt++) {
      const int k0 = kt * 64;

      bf16x8 kf[4][4];
#pragma unroll
      for (int s = 0; s < 4; s++)
#pragma unroll
        for (int j = 0; j < 4; j++)
          kf[s][j] = *(const bf16x8*)(Kp + (size_t)(k0 + j*16 + cl)*HD + s*32 + quad*8);

      f32x4 S[4];
#pragma unroll
      for (int j = 0; j < 4; j++) S[j] = (f32x4){0.f, 0.f, 0.f, 0.f};
#pragma unroll
      for (int s = 0; s < 4; s++)
#pragma unroll
        for (int j = 0; j < 4; j++)
          S[j] = __builtin_amdgcn_mfma_f32_16x16x32_bf16(qf[s], kf[s][j], S[j], 0, 0, 0);

      bf16x8 vf[2][8];
#pragma unroll
      for (int s2 = 0; s2 < 2; s2++)
#pragma unroll
        for (int d = 0; d < 8; d++)
          vf[s2][d] = *(const bf16x8*)(Vp + (size_t)(d*16 + cl)*TLEN + k0 + s2*32 + quad*8);

#pragma unroll
      for (int j = 0; j < 4; j++) {
        const int col = k0 + j*16 + cl;
#pragma unroll
        for (int r = 0; r < 4; r++) {
          const int row = q0 + wave*16 + quad*4 + r;
          const float sv = S[j][r] * scale;
          S[j][r] = (col <= row) ? sv : -1e9f;
        }
      }

      float alpha[4];
#pragma unroll
      for (int r = 0; r < 4; r++) {
        float mx = fmaxf(fmaxf(S[0][r], S[1][r]), fmaxf(S[2][r], S[3][r]));
#pragma unroll
        for (int off = 1; off < 16; off <<= 1) mx = fmaxf(mx, __shfl_xor(mx, off));
        const float mnew = fmaxf(m_i[r], mx);
        alpha[r] = __expf(m_i[r] - mnew);
        float rs = 0.f;
#pragma unroll
        for (int j = 0; j < 4; j++) {
          const float p = __expf(S[j][r] - mnew);
          S[j][r] = p;
          rs += p;
        }
#pragma unroll
        for (int off = 1; off < 16; off <<= 1) rs += __shfl_xor(rs, off);
        l_i[r] = l_i[r] * alpha[r] + rs;
        m_i[r] = mnew;
      }
#pragma unroll
      for (int d = 0; d < 8; d++)
#pragma unroll
        for (int r = 0; r < 4; r++) O[d][r] *= alpha[r];

#pragma unroll
      for (int j = 0; j < 4; j++)
#pragma unroll
        for (int r = 0; r < 4; r++) {
          const int row = quad*4 + r;
          int idx = row*64 + j*16 + cl;
          idx ^= (row & 7) << 3;
          Pw[idx] = (short)f2bf(S[j][r]);
        }

#pragma unroll
      for (int s2 = 0; s2 < 2; s2++) {
        int idx = cl*64 + s2*32 + quad*8;
        idx ^= (cl & 7) << 3;
        bf16x8 pf = *(const bf16x8*)(&Pw[idx]);
#pragma unroll
        for (int d = 0; d < 8; d++)
          O[d] = __builtin_amdgcn_mfma_f32_16x16x32_bf16(pf, vf[s2][d], O[d], 0, 0, 0);
      }
    }

#pragma unroll
    for (int d = 0; d < 8; d++) {
#pragma unroll
      for (int r = 0; r < 4; r++) {
        const int t = q0 + wave*16 + quad*4 + r;
        const float v = O[d][r] / l_i[r];
        yb[(size_t)(b*TLEN + t) * CDIM + h*HD + d*16 + cl] = (short)f2bf(v);
      }
    }
  }
}

// ---------------------------------------------------------------------------
// Memory plan. Workspace peak = 81 MB (same as all previously-passing rounds;
// R3's 93 MB layout is the suspected container-kill — ws_size unknown).
//   ws:   flag @ 0
//         qb  @  1MB (32MB)  q  [B,16,T,128] bf16
//         kb  @ 33MB ( 8MB)  k  [B,4,T,128]  bf16  -> wpb after attn (k dead)
//         vtb @ 41MB ( 8MB)  vT [B,4,128,T]  bf16
//         yb  @ 49MB (32MB)  y  [B,T,C]      bf16
//   d_out (64MB fp32, write-only until gemm1) doubles as scratch:
//         xb  @ d_out+0    (32MB) x bf16      — dead after gemm0
//         wab @ d_out+32MB (12MB) w_attn bf16 — dead after gemm0
// ---------------------------------------------------------------------------
extern "C" void kernel_launch(void* const* d_in, const int* in_sizes, int n_in,
                              void* d_out, int out_size, void* d_ws, size_t ws_size,
                              hipStream_t stream)
{
  const void* x      = d_in[0];   // [B,T,C]
  const void* w_attn = d_in[1];   // [3072,2048]
  const void* w_proj = d_in[2];   // [2048,2048]

  char* ws = (char*)d_ws;
  int*   flag = (int*)ws;
  short* qb  = (short*)(ws + (size_t) 1*1024*1024);
  short* kb  = (short*)(ws + (size_t)33*1024*1024);
  short* vtb = (short*)(ws + (size_t)41*1024*1024);
  short* yb  = (short*)(ws + (size_t)49*1024*1024);
  short* xb  = (short*)d_out;                              // scratch in output buf
  short* wab = (short*)((char*)d_out + (size_t)32*1024*1024);
  short* wpb = kb;                                         // alias: k dead after attn

  dim3 blk(256);
  detect_kernel<<<1, blk, 0, stream>>>(w_proj, flag);
  cvt_kernel<<<dim3((MROWS*CDIM/8)/256), blk, 0, stream>>>(x, xb, MROWS*CDIM/8, flag);
  cvt_kernel<<<dim3((3072*CDIM/8)/256), blk, 0, stream>>>(w_attn, wab, 3072*CDIM/8, flag);
  gemm_bt<0><<<dim3(3072/128, MROWS/128), blk, 0, stream>>>(xb, wab, qb, kb, vtb, nullptr, flag);
  rope_kernel<<<dim3((80*TLEN*64)/256), blk, 0, stream>>>(qb, kb);
  attn_kernel<<<dim3(TLEN/128, BSZ*NH), blk, 0, stream>>>(qb, kb, vtb, yb);
  cvt_kernel<<<dim3((CDIM*CDIM/8)/256), blk, 0, stream>>>(w_proj, wpb, CDIM*CDIM/8, flag);
  gemm_bt<1><<<dim3(CDIM/128, MROWS/128), blk, 0, stream>>>(yb, wpb, (short*)d_out,
                                                            nullptr, nullptr, (float*)d_out, flag);
}

// Round 5
// 616.965 us; speedup vs baseline: 2.3858x; 1.4561x over previous
//
#include <hip/hip_runtime.h>
#include <math.h>

#define NH   16
#define NKV  4
#define HD   128
#define BSZ  4
#define TLEN 2048
#define CDIM 2048
#define MROWS (BSZ*TLEN)   // 8192

typedef short bf16x8 __attribute__((ext_vector_type(8)));
typedef float f32x4  __attribute__((ext_vector_type(4)));
typedef int   int4v  __attribute__((ext_vector_type(4)));

__device__ inline float bf2f(unsigned short h) {
  union { unsigned u; float f; } x; x.u = ((unsigned)h) << 16; return x.f;
}
__device__ inline unsigned short f2bf(float f) {
  union { float f; unsigned u; } x; x.f = f;
  unsigned u = x.u;
  return (unsigned short)((u + 0x7FFFu + ((u >> 16) & 1u)) >> 16);
}

// Async global->LDS DMA, 16B per lane. LDS dest = wave-uniform base + lane*16.
__device__ inline void gload_lds16(const void* g, void* l) {
  __builtin_amdgcn_global_load_lds((const __attribute__((address_space(1))) void*)g,
                                   (__attribute__((address_space(3))) void*)l, 16, 0, 0);
}

// ---------------------------------------------------------------------------
// Dtype detector (unchanged): flag=1 => inputs are packed bf16.
// ---------------------------------------------------------------------------
__global__ void detect_kernel(const void* __restrict__ wproj, int* __restrict__ flag) {
  __shared__ int cnt;
  if (threadIdx.x == 0) cnt = 0;
  __syncthreads();
  const unsigned short* s = (const unsigned short*)wproj;
  unsigned short v = s[2 * threadIdx.x];          // 256 even shorts
  int e = (v >> 7) & 0xFF;
  if (e >= 90 && e <= 141) atomicAdd(&cnt, 1);
  __syncthreads();
  if (threadIdx.x == 0) *flag = (cnt >= 192) ? 1 : 0;
}

// Produce 8 contiguous bf16 from source (bf16 copy or fp32 convert).
__device__ inline void stage8(short* dst, const void* src, size_t eoff, int isbf) {
  if (isbf) {
    *(int4v*)dst = *(const int4v*)((const short*)src + eoff);
  } else {
    const f32x4* f = (const f32x4*)((const float*)src + eoff);
    f32x4 a = f[0], b = f[1];
    __align__(16) short t[8];
    t[0] = (short)f2bf(a[0]); t[1] = (short)f2bf(a[1]);
    t[2] = (short)f2bf(a[2]); t[3] = (short)f2bf(a[3]);
    t[4] = (short)f2bf(b[0]); t[5] = (short)f2bf(b[1]);
    t[6] = (short)f2bf(b[2]); t[7] = (short)f2bf(b[3]);
    *(int4v*)dst = *(int4v*)t;
  }
}

// ---------------------------------------------------------------------------
// One-shot convert/copy to packed bf16. 8 elems/thread, fully coalesced.
// ---------------------------------------------------------------------------
__global__ __launch_bounds__(256) void cvt_kernel(const void* __restrict__ src,
                                                  short* __restrict__ dst,
                                                  int n8, const int* __restrict__ flagp)
{
  const int fl = *flagp;
  const int i = blockIdx.x * 256 + threadIdx.x;
  if (i >= n8) return;
  __align__(16) short t[8];
  stage8(t, src, (size_t)i * 8, fl);
  *(int4v*)(dst + (size_t)i * 8) = *(int4v*)t;
}

// ---------------------------------------------------------------------------
// GEMM  C[m,n] = sum_k A[m,k] * W[n,k]   (bf16 inputs, fp32 accum)
// m97 structure (unchanged from R4, measured good).
// ---------------------------------------------------------------------------
template<int MODE>
__global__ __launch_bounds__(256) void gemm_bt(
    const short* __restrict__ A, const short* __restrict__ W,
    short* __restrict__ o0, short* __restrict__ o1, short* __restrict__ o2,
    float* __restrict__ o0f, const int* __restrict__ flagp)
{
  __shared__ __align__(16) short As[128*32];
  __shared__ __align__(16) short Bs[128*32];
  const int fl = *flagp;
  const int tid  = threadIdx.x;
  const int wave = tid >> 6;
  const int lane = tid & 63;
  const int cl   = lane & 15;
  const int quad = lane >> 4;
  const int m0 = blockIdx.y * 128;
  const int n0 = blockIdx.x * 128;
  const int wr = (wave >> 1) * 64;
  const int wc = (wave & 1) * 64;
  const int K = CDIM;
  const int rq = tid >> 2;             // 0..63
  const int cq = (tid & 3) << 3;       // 0,8,16,24
  const short* Ap = A + (size_t)(m0 + rq) * K + cq;
  const short* Wp = W + (size_t)(n0 + rq) * K + cq;
  short* AsW = As + wave * 512;        // + lane*8 shorts appended by HW
  short* BsW = Bs + wave * 512;
  const size_t rowskip = (size_t)64 * K;

  f32x4 acc[4][4];
#pragma unroll
  for (int i = 0; i < 4; i++)
#pragma unroll
    for (int j = 0; j < 4; j++) acc[i][j] = (f32x4){0.f, 0.f, 0.f, 0.f};

  for (int k0 = 0; k0 < K; k0 += 32) {
    gload_lds16(Ap + k0,           AsW);
    gload_lds16(Ap + k0 + rowskip, AsW + 2048);
    gload_lds16(Wp + k0,           BsW);
    gload_lds16(Wp + k0 + rowskip, BsW + 2048);
    __syncthreads();   // drains vmcnt (LDS-DMA) + lgkmcnt
    bf16x8 af[4], bfr[4];
#pragma unroll
    for (int i = 0; i < 4; i++) af[i]  = *(const bf16x8*)(&As[(wr + i*16 + cl)*32 + quad*8]);
#pragma unroll
    for (int j = 0; j < 4; j++) bfr[j] = *(const bf16x8*)(&Bs[(wc + j*16 + cl)*32 + quad*8]);
#pragma unroll
    for (int i = 0; i < 4; i++)
#pragma unroll
      for (int j = 0; j < 4; j++)
        acc[i][j] = __builtin_amdgcn_mfma_f32_16x16x32_bf16(af[i], bfr[j], acc[i][j], 0, 0, 0);
    __syncthreads();   // protect LDS from next-iter staging
  }

  // C/D layout (verified m89/m91): col = lane&15, row = quad*4 + reg.
#pragma unroll
  for (int i = 0; i < 4; i++) {
#pragma unroll
    for (int j = 0; j < 4; j++) {
#pragma unroll
      for (int r = 0; r < 4; r++) {
        const int gm = m0 + wr + i*16 + quad*4 + r;
        const int gn = n0 + wc + j*16 + cl;
        const float fv = acc[i][j][r];
        if (MODE == 1) {
          if (fl) o0[(size_t)gm * CDIM + gn] = (short)f2bf(fv);
          else    o0f[(size_t)gm * CDIM + gn] = fv;
        } else {
          const int b = gm >> 11;          // /TLEN
          const int t = gm & (TLEN - 1);
          const int head = gn >> 7;        // 0..23
          const int d = gn & (HD - 1);
          const unsigned short h = f2bf(fv);
          if (head < 16) {
            o0[(((size_t)(b*NH + head) * TLEN + t) << 7) + d] = (short)h;
          } else if (head < 20) {
            o1[(((size_t)(b*NKV + (head-16)) * TLEN + t) << 7) + d] = (short)h;
          } else {
            o2[(((size_t)(b*NKV + (head-20)) * HD + d) << 11) + t] = (short)h;  // vT[b][kv][d][t]
          }
        }
      }
    }
  }
}

// ---------------------------------------------------------------------------
// RoPE in place on q [B,16,T,128] and k [B,4,T,128]; interleaved pairs.
// ---------------------------------------------------------------------------
__global__ __launch_bounds__(256) void rope_kernel(short* __restrict__ qb,
                                                   short* __restrict__ kb)
{
  const int idx = blockIdx.x * 256 + threadIdx.x;   // exactly 80*2048*64 threads
  const int per_plane = TLEN * 64;
  const int plane = idx / per_plane;
  const int rem = idx - plane * per_plane;
  const int t = rem >> 6;
  const int i = rem & 63;
  short* base = (plane < 64) ? (qb + (size_t)plane * (TLEN*HD))
                             : (kb + (size_t)(plane - 64) * (TLEN*HD));
  const size_t off = (size_t)t * HD + 2*i;
  const float x1 = bf2f((unsigned short)base[off]);
  const float x2 = bf2f((unsigned short)base[off+1]);
  const float inv = __expf(-0.14391156847064198f * (float)i);  // 10000^(-2i/128)
  const float ang = (float)t * inv;
  float s, c;
  sincosf(ang, &s, &c);
  base[off]   = (short)f2bf(x1*c - x2*s);
  base[off+1] = (short)f2bf(x1*s + x2*c);
}

// ---------------------------------------------------------------------------
// Flash attention (causal), R5: cooperative double-buffered LDS staging.
//
// Why: R1-R4 showed the allocator pins attn at 92 VGPRs and serializes the
// 32 per-wave flat K/V loads (MfmaUtil 5.8%, latency-bound). global_load_lds
// staging costs ZERO VGPRs (vmcnt-counted DMA), is shared by all 4 waves
// (4x less fetch), and double-buffering overlaps next-tile DMA with this
// tile's softmax+MFMA. Single end-of-tile __syncthreads per tile (its
// vmcnt(0) drain lands after ~1-2k cy of compute has covered the latency).
//
// Swizzle (rule #21: linear LDS dest + inverse-swizzled SOURCE + same XOR on
// read): 16B-chunk index cc ^= (row&7). Without it, [row][128B+] row-major
// LDS tiles are 16-32-way bank conflicts on ds_read_b128.
//   K tile: 64 rows x 128 cols bf16 (16 chunks/row), read at chunk s*4+quad.
//   V tile: 128 rows x 64 cols bf16 (8 chunks/row),  read at chunk s2*4+quad.
// Both reads: row&7 == cl&7, so read chunk ^= (cl&7) -> 8 distinct bank
// groups across lanes.
// ---------------------------------------------------------------------------
__device__ inline void stage_tiles(short* Ks, short* Vs,
                                   const short* Kp, const short* Vp,
                                   int k0, int tid, int wave) {
  // K: 1024 chunks (64 rows x 16), 4 issues x 256 threads
#pragma unroll
  for (int i = 0; i < 4; i++) {
    const int chunk = i*256 + tid;
    const int row = chunk >> 4;
    const int cc  = (chunk & 15) ^ (row & 7);
    gload_lds16(Kp + (size_t)(k0 + row)*HD + cc*8,
                Ks + ((i*256 + wave*64) << 3));
  }
  // V: 1024 chunks (128 rows x 8), 4 issues x 256 threads
#pragma unroll
  for (int i = 0; i < 4; i++) {
    const int chunk = i*256 + tid;
    const int row = chunk >> 3;
    const int cc  = (chunk & 7) ^ (row & 7);
    gload_lds16(Vp + (size_t)row*TLEN + k0 + cc*8,
                Vs + ((i*256 + wave*64) << 3));
  }
}

__global__ __launch_bounds__(256) void attn_kernel(
    const short* __restrict__ qb, const short* __restrict__ kb,
    const short* __restrict__ vtb, short* __restrict__ yb)
{
  __shared__ __align__(16) short Ks[2][64*128];   // 32 KB
  __shared__ __align__(16) short Vs[2][128*64];   // 32 KB
  __shared__ short Plds[4][16][64];               //  8 KB  (72 KB total -> 2 blk/CU)
  const int tid  = threadIdx.x;
  const int wave = tid >> 6;
  const int lane = tid & 63;
  const int cl   = lane & 15;
  const int quad = lane >> 4;
  const int bh = blockIdx.y;
  const int b = bh >> 4, h = bh & 15;
  const int kvh = h >> 2;

  const short* Qp = qb  + (size_t)(b*NH  + h)   * TLEN * HD;
  const short* Kp = kb  + (size_t)(b*NKV + kvh) * TLEN * HD;
  const short* Vp = vtb + (size_t)(b*NKV + kvh) * HD * TLEN;
  short* Pw = &Plds[wave][0][0];
  const int swz = (cl & 7) << 3;   // read-side chunk XOR, in shorts

  const float scale = 0.08838834764831845f;  // 1/sqrt(128)

#pragma unroll 1
  for (int pass = 0; pass < 2; ++pass) {
    const int qi = pass ? (TLEN/64 - 1 - (int)blockIdx.x) : (int)blockIdx.x;
    const int q0 = qi * 64;
    const int ntiles = qi + 1;

    bf16x8 qf[4];
    const int qrow = q0 + wave*16 + cl;
#pragma unroll
    for (int s = 0; s < 4; s++)
      qf[s] = *(const bf16x8*)(Qp + (size_t)qrow*HD + s*32 + quad*8);

    f32x4 O[8];
#pragma unroll
    for (int d = 0; d < 8; d++) O[d] = (f32x4){0.f, 0.f, 0.f, 0.f};
    float m_i[4], l_i[4];
#pragma unroll
    for (int r = 0; r < 4; r++) { m_i[r] = -1e9f; l_i[r] = 0.f; }

    // prologue: stage tile 0
    stage_tiles(Ks[0], Vs[0], Kp, Vp, 0, tid, wave);
    __syncthreads();
    int cur = 0;

    for (int kt = 0; kt < ntiles; kt++) {
      const int k0 = kt * 64;

      // prefetch next tile into the other buffer (DMA flies under compute)
      if (kt + 1 < ntiles)
        stage_tiles(Ks[cur^1], Vs[cur^1], Kp, Vp, k0 + 64, tid, wave);

      const short* Kt = Ks[cur];
      const short* Vt = Vs[cur];

      // --- QK^T from LDS ---
      f32x4 S[4];
#pragma unroll
      for (int j = 0; j < 4; j++) S[j] = (f32x4){0.f, 0.f, 0.f, 0.f};
#pragma unroll
      for (int s = 0; s < 4; s++) {
        bf16x8 kfj[4];
#pragma unroll
        for (int j = 0; j < 4; j++)
          kfj[j] = *(const bf16x8*)(&Kt[(size_t)(j*16 + cl)*128 + ((((s*4 + quad) << 3) ^ swz))]);
#pragma unroll
        for (int j = 0; j < 4; j++)
          S[j] = __builtin_amdgcn_mfma_f32_16x16x32_bf16(qf[s], kfj[j], S[j], 0, 0, 0);
      }

      // --- causal mask + scale ---
#pragma unroll
      for (int j = 0; j < 4; j++) {
        const int col = k0 + j*16 + cl;
#pragma unroll
        for (int r = 0; r < 4; r++) {
          const int row = q0 + wave*16 + quad*4 + r;
          const float sv = S[j][r] * scale;
          S[j][r] = (col <= row) ? sv : -1e9f;
        }
      }

      // --- online softmax ---
      float alpha[4];
#pragma unroll
      for (int r = 0; r < 4; r++) {
        float mx = fmaxf(fmaxf(S[0][r], S[1][r]), fmaxf(S[2][r], S[3][r]));
#pragma unroll
        for (int off = 1; off < 16; off <<= 1) mx = fmaxf(mx, __shfl_xor(mx, off));
        const float mnew = fmaxf(m_i[r], mx);
        alpha[r] = __expf(m_i[r] - mnew);
        float rs = 0.f;
#pragma unroll
        for (int j = 0; j < 4; j++) {
          const float p = __expf(S[j][r] - mnew);
          S[j][r] = p;
          rs += p;
        }
#pragma unroll
        for (int off = 1; off < 16; off <<= 1) rs += __shfl_xor(rs, off);
        l_i[r] = l_i[r] * alpha[r] + rs;
        m_i[r] = mnew;
      }
#pragma unroll
      for (int d = 0; d < 8; d++)
#pragma unroll
        for (int r = 0; r < 4; r++) O[d][r] *= alpha[r];

      // --- P -> LDS (wave-private, XOR-swizzled; no barrier needed) ---
#pragma unroll
      for (int j = 0; j < 4; j++)
#pragma unroll
        for (int r = 0; r < 4; r++) {
          const int row = quad*4 + r;
          int idx = row*64 + j*16 + cl;
          idx ^= (row & 7) << 3;
          Pw[idx] = (short)f2bf(S[j][r]);
        }

      // --- PV: P from LDS (A-operand), V from LDS tile ---
#pragma unroll
      for (int s2 = 0; s2 < 2; s2++) {
        int idx = cl*64 + s2*32 + quad*8;
        idx ^= (cl & 7) << 3;
        bf16x8 pf = *(const bf16x8*)(&Pw[idx]);
#pragma unroll
        for (int d = 0; d < 8; d++) {
          bf16x8 vfd = *(const bf16x8*)(&Vt[(size_t)(d*16 + cl)*64 + ((((s2*4 + quad) << 3) ^ swz))]);
          O[d] = __builtin_amdgcn_mfma_f32_16x16x32_bf16(pf, vfd, O[d], 0, 0, 0);
        }
      }

      __syncthreads();   // all waves done with buf[cur]; prefetch drained
      cur ^= 1;
    }

#pragma unroll
    for (int d = 0; d < 8; d++) {
#pragma unroll
      for (int r = 0; r < 4; r++) {
        const int t = q0 + wave*16 + quad*4 + r;
        const float v = O[d][r] / l_i[r];
        yb[(size_t)(b*TLEN + t) * CDIM + h*HD + d*16 + cl] = (short)f2bf(v);
      }
    }
  }
}

// ---------------------------------------------------------------------------
// Memory plan (81 MB workspace peak, same as R4-passing):
//   ws:   flag @ 0
//         qb  @  1MB (32MB)  q  [B,16,T,128] bf16
//         kb  @ 33MB ( 8MB)  k  [B,4,T,128]  bf16  -> wpb after attn (k dead)
//         vtb @ 41MB ( 8MB)  vT [B,4,128,T]  bf16
//         yb  @ 49MB (32MB)  y  [B,T,C]      bf16
//   d_out (64MB fp32, write-only until gemm1) doubles as scratch:
//         xb  @ d_out+0    (32MB) x bf16      — dead after gemm0
//         wab @ d_out+32MB (12MB) w_attn bf16 — dead after gemm0
// ---------------------------------------------------------------------------
extern "C" void kernel_launch(void* const* d_in, const int* in_sizes, int n_in,
                              void* d_out, int out_size, void* d_ws, size_t ws_size,
                              hipStream_t stream)
{
  const void* x      = d_in[0];   // [B,T,C]
  const void* w_attn = d_in[1];   // [3072,2048]
  const void* w_proj = d_in[2];   // [2048,2048]

  char* ws = (char*)d_ws;
  int*   flag = (int*)ws;
  short* qb  = (short*)(ws + (size_t) 1*1024*1024);
  short* kb  = (short*)(ws + (size_t)33*1024*1024);
  short* vtb = (short*)(ws + (size_t)41*1024*1024);
  short* yb  = (short*)(ws + (size_t)49*1024*1024);
  short* xb  = (short*)d_out;                              // scratch in output buf
  short* wab = (short*)((char*)d_out + (size_t)32*1024*1024);
  short* wpb = kb;                                         // alias: k dead after attn

  dim3 blk(256);
  detect_kernel<<<1, blk, 0, stream>>>(w_proj, flag);
  cvt_kernel<<<dim3((MROWS*CDIM/8)/256), blk, 0, stream>>>(x, xb, MROWS*CDIM/8, flag);
  cvt_kernel<<<dim3((3072*CDIM/8)/256), blk, 0, stream>>>(w_attn, wab, 3072*CDIM/8, flag);
  gemm_bt<0><<<dim3(3072/128, MROWS/128), blk, 0, stream>>>(xb, wab, qb, kb, vtb, nullptr, flag);
  rope_kernel<<<dim3((80*TLEN*64)/256), blk, 0, stream>>>(qb, kb);
  attn_kernel<<<dim3(TLEN/128, BSZ*NH), blk, 0, stream>>>(qb, kb, vtb, yb);
  cvt_kernel<<<dim3((CDIM*CDIM/8)/256), blk, 0, stream>>>(w_proj, wpb, CDIM*CDIM/8, flag);
  gemm_bt<1><<<dim3(CDIM/128, MROWS/128), blk, 0, stream>>>(yb, wpb, (short*)d_out,
                                                            nullptr, nullptr, (float*)d_out, flag);
}

// Round 6
// 592.382 us; speedup vs baseline: 2.4849x; 1.0415x over previous
//
#include <hip/hip_runtime.h>
#include <math.h>

#define NH   16
#define NKV  4
#define HD   128
#define BSZ  4
#define TLEN 2048
#define CDIM 2048
#define MROWS (BSZ*TLEN)   // 8192

typedef short bf16x8 __attribute__((ext_vector_type(8)));
typedef float f32x4  __attribute__((ext_vector_type(4)));
typedef int   int4v  __attribute__((ext_vector_type(4)));

__device__ inline float bf2f(unsigned short h) {
  union { unsigned u; float f; } x; x.u = ((unsigned)h) << 16; return x.f;
}
__device__ inline unsigned short f2bf(float f) {
  union { float f; unsigned u; } x; x.f = f;
  unsigned u = x.u;
  return (unsigned short)((u + 0x7FFFu + ((u >> 16) & 1u)) >> 16);
}

// Async global->LDS DMA, 16B per lane. LDS dest = wave-uniform base + lane*16.
__device__ inline void gload_lds16(const void* g, void* l) {
  __builtin_amdgcn_global_load_lds((const __attribute__((address_space(1))) void*)g,
                                   (__attribute__((address_space(3))) void*)l, 16, 0, 0);
}

// ---------------------------------------------------------------------------
// Dtype detector (unchanged): flag=1 => inputs are packed bf16.
// ---------------------------------------------------------------------------
__global__ void detect_kernel(const void* __restrict__ wproj, int* __restrict__ flag) {
  __shared__ int cnt;
  if (threadIdx.x == 0) cnt = 0;
  __syncthreads();
  const unsigned short* s = (const unsigned short*)wproj;
  unsigned short v = s[2 * threadIdx.x];          // 256 even shorts
  int e = (v >> 7) & 0xFF;
  if (e >= 90 && e <= 141) atomicAdd(&cnt, 1);
  __syncthreads();
  if (threadIdx.x == 0) *flag = (cnt >= 192) ? 1 : 0;
}

// Produce 8 contiguous bf16 from source (bf16 copy or fp32 convert).
__device__ inline void stage8(short* dst, const void* src, size_t eoff, int isbf) {
  if (isbf) {
    *(int4v*)dst = *(const int4v*)((const short*)src + eoff);
  } else {
    const f32x4* f = (const f32x4*)((const float*)src + eoff);
    f32x4 a = f[0], b = f[1];
    __align__(16) short t[8];
    t[0] = (short)f2bf(a[0]); t[1] = (short)f2bf(a[1]);
    t[2] = (short)f2bf(a[2]); t[3] = (short)f2bf(a[3]);
    t[4] = (short)f2bf(b[0]); t[5] = (short)f2bf(b[1]);
    t[6] = (short)f2bf(b[2]); t[7] = (short)f2bf(b[3]);
    *(int4v*)dst = *(int4v*)t;
  }
}

// ---------------------------------------------------------------------------
// One-shot convert/copy to packed bf16. 8 elems/thread, fully coalesced.
// ---------------------------------------------------------------------------
__global__ __launch_bounds__(256) void cvt_kernel(const void* __restrict__ src,
                                                  short* __restrict__ dst,
                                                  int n8, const int* __restrict__ flagp)
{
  const int fl = *flagp;
  const int i = blockIdx.x * 256 + threadIdx.x;
  if (i >= n8) return;
  __align__(16) short t[8];
  stage8(t, src, (size_t)i * 8, fl);
  *(int4v*)(dst + (size_t)i * 8) = *(int4v*)t;
}

// ---------------------------------------------------------------------------
// GEMM  C[m,n] = sum_k A[m,k] * W[n,k]   (bf16 inputs, fp32 accum)
// m97 structure + R6: bijective XCD-aware block swizzle (T1; grids are %8==0)
// so consecutive logical tiles (sharing the A-panel) land on one XCD's L2.
// ---------------------------------------------------------------------------
template<int MODE>
__global__ __launch_bounds__(256) void gemm_bt(
    const short* __restrict__ A, const short* __restrict__ W,
    short* __restrict__ o0, short* __restrict__ o1, short* __restrict__ o2,
    float* __restrict__ o0f, const int* __restrict__ flagp)
{
  __shared__ __align__(16) short As[128*32];
  __shared__ __align__(16) short Bs[128*32];
  const int fl = *flagp;
  const int tid  = threadIdx.x;
  const int wave = tid >> 6;
  const int lane = tid & 63;
  const int cl   = lane & 15;
  const int quad = lane >> 4;
  // XCD swizzle: hardware blockIdx round-robins the 8 XCDs; remap so each XCD
  // owns a contiguous chunk of the logical (row-major) tile order.
  const int nwgx = gridDim.x;
  int wg = (int)blockIdx.y * nwgx + (int)blockIdx.x;
  const int cpx = (nwgx * (int)gridDim.y) >> 3;    // nwg/8, nwg%8==0
  wg = (wg & 7) * cpx + (wg >> 3);
  const int m0 = (wg / nwgx) * 128;
  const int n0 = (wg % nwgx) * 128;
  const int wr = (wave >> 1) * 64;
  const int wc = (wave & 1) * 64;
  const int K = CDIM;
  const int rq = tid >> 2;             // 0..63
  const int cq = (tid & 3) << 3;       // 0,8,16,24
  const short* Ap = A + (size_t)(m0 + rq) * K + cq;
  const short* Wp = W + (size_t)(n0 + rq) * K + cq;
  short* AsW = As + wave * 512;        // + lane*8 shorts appended by HW
  short* BsW = Bs + wave * 512;
  const size_t rowskip = (size_t)64 * K;

  f32x4 acc[4][4];
#pragma unroll
  for (int i = 0; i < 4; i++)
#pragma unroll
    for (int j = 0; j < 4; j++) acc[i][j] = (f32x4){0.f, 0.f, 0.f, 0.f};

  for (int k0 = 0; k0 < K; k0 += 32) {
    gload_lds16(Ap + k0,           AsW);
    gload_lds16(Ap + k0 + rowskip, AsW + 2048);
    gload_lds16(Wp + k0,           BsW);
    gload_lds16(Wp + k0 + rowskip, BsW + 2048);
    __syncthreads();   // drains vmcnt (LDS-DMA) + lgkmcnt
    bf16x8 af[4], bfr[4];
#pragma unroll
    for (int i = 0; i < 4; i++) af[i]  = *(const bf16x8*)(&As[(wr + i*16 + cl)*32 + quad*8]);
#pragma unroll
    for (int j = 0; j < 4; j++) bfr[j] = *(const bf16x8*)(&Bs[(wc + j*16 + cl)*32 + quad*8]);
#pragma unroll
    for (int i = 0; i < 4; i++)
#pragma unroll
      for (int j = 0; j < 4; j++)
        acc[i][j] = __builtin_amdgcn_mfma_f32_16x16x32_bf16(af[i], bfr[j], acc[i][j], 0, 0, 0);
    __syncthreads();   // protect LDS from next-iter staging
  }

  // C/D layout (verified m89/m91): col = lane&15, row = quad*4 + reg.
#pragma unroll
  for (int i = 0; i < 4; i++) {
#pragma unroll
    for (int j = 0; j < 4; j++) {
#pragma unroll
      for (int r = 0; r < 4; r++) {
        const int gm = m0 + wr + i*16 + quad*4 + r;
        const int gn = n0 + wc + j*16 + cl;
        const float fv = acc[i][j][r];
        if (MODE == 1) {
          if (fl) o0[(size_t)gm * CDIM + gn] = (short)f2bf(fv);
          else    o0f[(size_t)gm * CDIM + gn] = fv;
        } else {
          const int b = gm >> 11;          // /TLEN
          const int t = gm & (TLEN - 1);
          const int head = gn >> 7;        // 0..23
          const int d = gn & (HD - 1);
          const unsigned short h = f2bf(fv);
          if (head < 16) {
            o0[(((size_t)(b*NH + head) * TLEN + t) << 7) + d] = (short)h;
          } else if (head < 20) {
            o1[(((size_t)(b*NKV + (head-16)) * TLEN + t) << 7) + d] = (short)h;
          } else {
            o2[(((size_t)(b*NKV + (head-20)) * HD + d) << 11) + t] = (short)h;  // vT[b][kv][d][t]
          }
        }
      }
    }
  }
}

// ---------------------------------------------------------------------------
// RoPE in place on q [B,16,T,128] and k [B,4,T,128]; interleaved pairs.
// R6: fold the attention scale 1/sqrt(128) into q here (free — q is being
// rewritten anyway); attn no longer multiplies by scale.
// ---------------------------------------------------------------------------
__global__ __launch_bounds__(256) void rope_kernel(short* __restrict__ qb,
                                                   short* __restrict__ kb)
{
  const int idx = blockIdx.x * 256 + threadIdx.x;   // exactly 80*2048*64 threads
  const int per_plane = TLEN * 64;
  const int plane = idx / per_plane;
  const int rem = idx - plane * per_plane;
  const int t = rem >> 6;
  const int i = rem & 63;
  short* base = (plane < 64) ? (qb + (size_t)plane * (TLEN*HD))
                             : (kb + (size_t)(plane - 64) * (TLEN*HD));
  const size_t off = (size_t)t * HD + 2*i;
  const float x1 = bf2f((unsigned short)base[off]);
  const float x2 = bf2f((unsigned short)base[off+1]);
  const float inv = __expf(-0.14391156847064198f * (float)i);  // 10000^(-2i/128)
  const float ang = (float)t * inv;
  float s, c;
  sincosf(ang, &s, &c);
  const float qscale = (plane < 64) ? 0.08838834764831845f : 1.0f;  // 1/sqrt(128) on q only
  base[off]   = (short)f2bf((x1*c - x2*s) * qscale);
  base[off+1] = (short)f2bf((x1*s + x2*c) * qscale);
}

// ---------------------------------------------------------------------------
// Flash attention (causal), R6: VALU diet on the R5 structure.
//  - scale folded into q (rope) -> no per-element scale mul
//  - causal mask only on the diagonal tile (kt == ntiles-1); full tiles skip
//    the 48-op mask/compare block entirely (wave-uniform branch)
//  - defer-max (T13, THR=8): skip O-rescale (32 mul + 4 exp) unless the row
//    max grew by >8; P bounded by e^8, harmless in fp32 accum
//  - epilogue: 4 divides + 32 mul instead of 32 divides
// R5 staging (coop double-buffered global_load_lds, swizzled) unchanged.
// ---------------------------------------------------------------------------
__device__ inline void stage_tiles(short* Ks, short* Vs,
                                   const short* Kp, const short* Vp,
                                   int k0, int tid, int wave) {
  // K: 1024 chunks (64 rows x 16), 4 issues x 256 threads
#pragma unroll
  for (int i = 0; i < 4; i++) {
    const int chunk = i*256 + tid;
    const int row = chunk >> 4;
    const int cc  = (chunk & 15) ^ (row & 7);
    gload_lds16(Kp + (size_t)(k0 + row)*HD + cc*8,
                Ks + ((i*256 + wave*64) << 3));
  }
  // V: 1024 chunks (128 rows x 8), 4 issues x 256 threads
#pragma unroll
  for (int i = 0; i < 4; i++) {
    const int chunk = i*256 + tid;
    const int row = chunk >> 3;
    const int cc  = (chunk & 7) ^ (row & 7);
    gload_lds16(Vp + (size_t)row*TLEN + k0 + cc*8,
                Vs + ((i*256 + wave*64) << 3));
  }
}

__global__ __launch_bounds__(256) void attn_kernel(
    const short* __restrict__ qb, const short* __restrict__ kb,
    const short* __restrict__ vtb, short* __restrict__ yb)
{
  __shared__ __align__(16) short Ks[2][64*128];   // 32 KB
  __shared__ __align__(16) short Vs[2][128*64];   // 32 KB
  __shared__ short Plds[4][16][64];               //  8 KB  (72 KB total -> 2 blk/CU)
  const int tid  = threadIdx.x;
  const int wave = tid >> 6;
  const int lane = tid & 63;
  const int cl   = lane & 15;
  const int quad = lane >> 4;
  const int bh = blockIdx.y;
  const int b = bh >> 4, h = bh & 15;
  const int kvh = h >> 2;

  const short* Qp = qb  + (size_t)(b*NH  + h)   * TLEN * HD;
  const short* Kp = kb  + (size_t)(b*NKV + kvh) * TLEN * HD;
  const short* Vp = vtb + (size_t)(b*NKV + kvh) * HD * TLEN;
  short* Pw = &Plds[wave][0][0];
  const int swz = (cl & 7) << 3;   // read-side chunk XOR, in shorts

#pragma unroll 1
  for (int pass = 0; pass < 2; ++pass) {
    const int qi = pass ? (TLEN/64 - 1 - (int)blockIdx.x) : (int)blockIdx.x;
    const int q0 = qi * 64;
    const int ntiles = qi + 1;

    bf16x8 qf[4];
    const int qrow = q0 + wave*16 + cl;
#pragma unroll
    for (int s = 0; s < 4; s++)
      qf[s] = *(const bf16x8*)(Qp + (size_t)qrow*HD + s*32 + quad*8);

    f32x4 O[8];
#pragma unroll
    for (int d = 0; d < 8; d++) O[d] = (f32x4){0.f, 0.f, 0.f, 0.f};
    float m_i[4], l_i[4];
#pragma unroll
    for (int r = 0; r < 4; r++) { m_i[r] = -1e9f; l_i[r] = 0.f; }

    // prologue: stage tile 0
    stage_tiles(Ks[0], Vs[0], Kp, Vp, 0, tid, wave);
    __syncthreads();
    int cur = 0;

    for (int kt = 0; kt < ntiles; kt++) {
      const int k0 = kt * 64;

      // prefetch next tile into the other buffer (DMA flies under compute)
      if (kt + 1 < ntiles)
        stage_tiles(Ks[cur^1], Vs[cur^1], Kp, Vp, k0 + 64, tid, wave);

      const short* Kt = Ks[cur];
      const short* Vt = Vs[cur];

      // --- QK^T from LDS (q pre-scaled by 1/sqrt(128)) ---
      f32x4 S[4];
#pragma unroll
      for (int j = 0; j < 4; j++) S[j] = (f32x4){0.f, 0.f, 0.f, 0.f};
#pragma unroll
      for (int s = 0; s < 4; s++) {
        bf16x8 kfj[4];
#pragma unroll
        for (int j = 0; j < 4; j++)
          kfj[j] = *(const bf16x8*)(&Kt[(size_t)(j*16 + cl)*128 + ((((s*4 + quad) << 3) ^ swz))]);
#pragma unroll
        for (int j = 0; j < 4; j++)
          S[j] = __builtin_amdgcn_mfma_f32_16x16x32_bf16(qf[s], kfj[j], S[j], 0, 0, 0);
      }

      // --- causal mask: diagonal tile only (full tiles have col < row) ---
      if (kt == ntiles - 1) {
#pragma unroll
        for (int j = 0; j < 4; j++) {
          const int col = k0 + j*16 + cl;
#pragma unroll
          for (int r = 0; r < 4; r++) {
            const int row = q0 + wave*16 + quad*4 + r;
            if (col > row) S[j][r] = -1e9f;
          }
        }
      }

      // --- row max ---
      float pmax[4];
#pragma unroll
      for (int r = 0; r < 4; r++) {
        float mx = fmaxf(fmaxf(S[0][r], S[1][r]), fmaxf(S[2][r], S[3][r]));
#pragma unroll
        for (int off = 1; off < 16; off <<= 1) mx = fmaxf(mx, __shfl_xor(mx, off));
        pmax[r] = mx;
      }
      // --- defer-max (T13, THR=8): rescale only when max grew materially ---
      const int ok = (pmax[0] - m_i[0] <= 8.f) && (pmax[1] - m_i[1] <= 8.f) &&
                     (pmax[2] - m_i[2] <= 8.f) && (pmax[3] - m_i[3] <= 8.f);
      if (!__all(ok)) {
#pragma unroll
        for (int r = 0; r < 4; r++) {
          const float mnew = fmaxf(m_i[r], pmax[r]);
          const float alpha = __expf(m_i[r] - mnew);
          l_i[r] *= alpha;
          m_i[r] = mnew;
#pragma unroll
          for (int d = 0; d < 8; d++) O[d][r] *= alpha;
        }
      }
      // --- P = exp(S - m), row sums ---
#pragma unroll
      for (int r = 0; r < 4; r++) {
        float rs = 0.f;
#pragma unroll
        for (int j = 0; j < 4; j++) {
          const float p = __expf(S[j][r] - m_i[r]);
          S[j][r] = p;
          rs += p;
        }
#pragma unroll
        for (int off = 1; off < 16; off <<= 1) rs += __shfl_xor(rs, off);
        l_i[r] += rs;
      }

      // --- P -> LDS (wave-private, XOR-swizzled; no barrier needed) ---
#pragma unroll
      for (int j = 0; j < 4; j++)
#pragma unroll
        for (int r = 0; r < 4; r++) {
          const int row = quad*4 + r;
          int idx = row*64 + j*16 + cl;
          idx ^= (row & 7) << 3;
          Pw[idx] = (short)f2bf(S[j][r]);
        }

      // --- PV: P from LDS (A-operand), V from LDS tile ---
#pragma unroll
      for (int s2 = 0; s2 < 2; s2++) {
        int idx = cl*64 + s2*32 + quad*8;
        idx ^= (cl & 7) << 3;
        bf16x8 pf = *(const bf16x8*)(&Pw[idx]);
#pragma unroll
        for (int d = 0; d < 8; d++) {
          bf16x8 vfd = *(const bf16x8*)(&Vt[(size_t)(d*16 + cl)*64 + ((((s2*4 + quad) << 3) ^ swz))]);
          O[d] = __builtin_amdgcn_mfma_f32_16x16x32_bf16(pf, vfd, O[d], 0, 0, 0);
        }
      }

      __syncthreads();   // all waves done with buf[cur]; prefetch drained
      cur ^= 1;
    }

    float linv[4];
#pragma unroll
    for (int r = 0; r < 4; r++) linv[r] = 1.0f / l_i[r];
#pragma unroll
    for (int d = 0; d < 8; d++) {
#pragma unroll
      for (int r = 0; r < 4; r++) {
        const int t = q0 + wave*16 + quad*4 + r;
        yb[(size_t)(b*TLEN + t) * CDIM + h*HD + d*16 + cl] = (short)f2bf(O[d][r] * linv[r]);
      }
    }
  }
}

// ---------------------------------------------------------------------------
// Memory plan (81 MB workspace peak, same as R4/R5-passing):
//   ws:   flag @ 0
//         qb  @  1MB (32MB)  q  [B,16,T,128] bf16
//         kb  @ 33MB ( 8MB)  k  [B,4,T,128]  bf16  -> wpb after attn (k dead)
//         vtb @ 41MB ( 8MB)  vT [B,4,128,T]  bf16
//         yb  @ 49MB (32MB)  y  [B,T,C]      bf16
//   d_out (64MB fp32, write-only until gemm1) doubles as scratch:
//         xb  @ d_out+0    (32MB) x bf16      — dead after gemm0
//         wab @ d_out+32MB (12MB) w_attn bf16 — dead after gemm0
// ---------------------------------------------------------------------------
extern "C" void kernel_launch(void* const* d_in, const int* in_sizes, int n_in,
                              void* d_out, int out_size, void* d_ws, size_t ws_size,
                              hipStream_t stream)
{
  const void* x      = d_in[0];   // [B,T,C]
  const void* w_attn = d_in[1];   // [3072,2048]
  const void* w_proj = d_in[2];   // [2048,2048]

  char* ws = (char*)d_ws;
  int*   flag = (int*)ws;
  short* qb  = (short*)(ws + (size_t) 1*1024*1024);
  short* kb  = (short*)(ws + (size_t)33*1024*1024);
  short* vtb = (short*)(ws + (size_t)41*1024*1024);
  short* yb  = (short*)(ws + (size_t)49*1024*1024);
  short* xb  = (short*)d_out;                              // scratch in output buf
  short* wab = (short*)((char*)d_out + (size_t)32*1024*1024);
  short* wpb = kb;                                         // alias: k dead after attn

  dim3 blk(256);
  detect_kernel<<<1, blk, 0, stream>>>(w_proj, flag);
  cvt_kernel<<<dim3((MROWS*CDIM/8)/256), blk, 0, stream>>>(x, xb, MROWS*CDIM/8, flag);
  cvt_kernel<<<dim3((3072*CDIM/8)/256), blk, 0, stream>>>(w_attn, wab, 3072*CDIM/8, flag);
  gemm_bt<0><<<dim3(3072/128, MROWS/128), blk, 0, stream>>>(xb, wab, qb, kb, vtb, nullptr, flag);
  rope_kernel<<<dim3((80*TLEN*64)/256), blk, 0, stream>>>(qb, kb);
  attn_kernel<<<dim3(TLEN/128, BSZ*NH), blk, 0, stream>>>(qb, kb, vtb, yb);
  cvt_kernel<<<dim3((CDIM*CDIM/8)/256), blk, 0, stream>>>(w_proj, wpb, CDIM*CDIM/8, flag);
  gemm_bt<1><<<dim3(CDIM/128, MROWS/128), blk, 0, stream>>>(yb, wpb, (short*)d_out,
                                                            nullptr, nullptr, (float*)d_out, flag);
}

// Round 7
// 553.708 us; speedup vs baseline: 2.6584x; 1.0698x over previous
//
#include <hip/hip_runtime.h>
#include <math.h>

#define NH   16
#define NKV  4
#define HD   128
#define BSZ  4
#define TLEN 2048
#define CDIM 2048
#define MROWS (BSZ*TLEN)   // 8192

typedef short bf16x8 __attribute__((ext_vector_type(8)));
typedef float f32x4  __attribute__((ext_vector_type(4)));
typedef int   int4v  __attribute__((ext_vector_type(4)));

__device__ inline float bf2f(unsigned short h) {
  union { unsigned u; float f; } x; x.u = ((unsigned)h) << 16; return x.f;
}
__device__ inline unsigned short f2bf(float f) {
  union { float f; unsigned u; } x; x.f = f;
  unsigned u = x.u;
  return (unsigned short)((u + 0x7FFFu + ((u >> 16) & 1u)) >> 16);
}

// Async global->LDS DMA, 16B per lane. LDS dest = wave-uniform base + lane*16.
__device__ inline void gload_lds16(const void* g, void* l) {
  __builtin_amdgcn_global_load_lds((const __attribute__((address_space(1))) void*)g,
                                   (__attribute__((address_space(3))) void*)l, 16, 0, 0);
}

// ---------------------------------------------------------------------------
// Dtype detector (unchanged): flag=1 => inputs are packed bf16.
// ---------------------------------------------------------------------------
__global__ void detect_kernel(const void* __restrict__ wproj, int* __restrict__ flag) {
  __shared__ int cnt;
  if (threadIdx.x == 0) cnt = 0;
  __syncthreads();
  const unsigned short* s = (const unsigned short*)wproj;
  unsigned short v = s[2 * threadIdx.x];          // 256 even shorts
  int e = (v >> 7) & 0xFF;
  if (e >= 90 && e <= 141) atomicAdd(&cnt, 1);
  __syncthreads();
  if (threadIdx.x == 0) *flag = (cnt >= 192) ? 1 : 0;
}

// Produce 8 contiguous bf16 from source (bf16 copy or fp32 convert).
__device__ inline void stage8(short* dst, const void* src, size_t eoff, int isbf) {
  if (isbf) {
    *(int4v*)dst = *(const int4v*)((const short*)src + eoff);
  } else {
    const f32x4* f = (const f32x4*)((const float*)src + eoff);
    f32x4 a = f[0], b = f[1];
    __align__(16) short t[8];
    t[0] = (short)f2bf(a[0]); t[1] = (short)f2bf(a[1]);
    t[2] = (short)f2bf(a[2]); t[3] = (short)f2bf(a[3]);
    t[4] = (short)f2bf(b[0]); t[5] = (short)f2bf(b[1]);
    t[6] = (short)f2bf(b[2]); t[7] = (short)f2bf(b[3]);
    *(int4v*)dst = *(int4v*)t;
  }
}

// ---------------------------------------------------------------------------
// One-shot convert/copy to packed bf16. 8 elems/thread, fully coalesced.
// ---------------------------------------------------------------------------
__global__ __launch_bounds__(256) void cvt_kernel(const void* __restrict__ src,
                                                  short* __restrict__ dst,
                                                  int n8, const int* __restrict__ flagp)
{
  const int fl = *flagp;
  const int i = blockIdx.x * 256 + threadIdx.x;
  if (i >= n8) return;
  __align__(16) short t[8];
  stage8(t, src, (size_t)i * 8, fl);
  *(int4v*)(dst + (size_t)i * 8) = *(int4v*)t;
}

// ---------------------------------------------------------------------------
// GEMM  C[m,n] = sum_k A[m,k] * W[n,k]   (bf16 inputs, fp32 accum)
// m97 structure + bijective XCD swizzle (unchanged from R6).
// ---------------------------------------------------------------------------
template<int MODE>
__global__ __launch_bounds__(256) void gemm_bt(
    const short* __restrict__ A, const short* __restrict__ W,
    short* __restrict__ o0, short* __restrict__ o1, short* __restrict__ o2,
    float* __restrict__ o0f, const int* __restrict__ flagp)
{
  __shared__ __align__(16) short As[128*32];
  __shared__ __align__(16) short Bs[128*32];
  const int fl = *flagp;
  const int tid  = threadIdx.x;
  const int wave = tid >> 6;
  const int lane = tid & 63;
  const int cl   = lane & 15;
  const int quad = lane >> 4;
  const int nwgx = gridDim.x;
  int wg = (int)blockIdx.y * nwgx + (int)blockIdx.x;
  const int cpx = (nwgx * (int)gridDim.y) >> 3;    // nwg/8, nwg%8==0
  wg = (wg & 7) * cpx + (wg >> 3);
  const int m0 = (wg / nwgx) * 128;
  const int n0 = (wg % nwgx) * 128;
  const int wr = (wave >> 1) * 64;
  const int wc = (wave & 1) * 64;
  const int K = CDIM;
  const int rq = tid >> 2;             // 0..63
  const int cq = (tid & 3) << 3;       // 0,8,16,24
  const short* Ap = A + (size_t)(m0 + rq) * K + cq;
  const short* Wp = W + (size_t)(n0 + rq) * K + cq;
  short* AsW = As + wave * 512;        // + lane*8 shorts appended by HW
  short* BsW = Bs + wave * 512;
  const size_t rowskip = (size_t)64 * K;

  f32x4 acc[4][4];
#pragma unroll
  for (int i = 0; i < 4; i++)
#pragma unroll
    for (int j = 0; j < 4; j++) acc[i][j] = (f32x4){0.f, 0.f, 0.f, 0.f};

  for (int k0 = 0; k0 < K; k0 += 32) {
    gload_lds16(Ap + k0,           AsW);
    gload_lds16(Ap + k0 + rowskip, AsW + 2048);
    gload_lds16(Wp + k0,           BsW);
    gload_lds16(Wp + k0 + rowskip, BsW + 2048);
    __syncthreads();   // drains vmcnt (LDS-DMA) + lgkmcnt
    bf16x8 af[4], bfr[4];
#pragma unroll
    for (int i = 0; i < 4; i++) af[i]  = *(const bf16x8*)(&As[(wr + i*16 + cl)*32 + quad*8]);
#pragma unroll
    for (int j = 0; j < 4; j++) bfr[j] = *(const bf16x8*)(&Bs[(wc + j*16 + cl)*32 + quad*8]);
#pragma unroll
    for (int i = 0; i < 4; i++)
#pragma unroll
      for (int j = 0; j < 4; j++)
        acc[i][j] = __builtin_amdgcn_mfma_f32_16x16x32_bf16(af[i], bfr[j], acc[i][j], 0, 0, 0);
    __syncthreads();   // protect LDS from next-iter staging
  }

  // C/D layout (verified m89/m91): col = lane&15, row = quad*4 + reg.
#pragma unroll
  for (int i = 0; i < 4; i++) {
#pragma unroll
    for (int j = 0; j < 4; j++) {
#pragma unroll
      for (int r = 0; r < 4; r++) {
        const int gm = m0 + wr + i*16 + quad*4 + r;
        const int gn = n0 + wc + j*16 + cl;
        const float fv = acc[i][j][r];
        if (MODE == 1) {
          if (fl) o0[(size_t)gm * CDIM + gn] = (short)f2bf(fv);
          else    o0f[(size_t)gm * CDIM + gn] = fv;
        } else {
          const int b = gm >> 11;          // /TLEN
          const int t = gm & (TLEN - 1);
          const int head = gn >> 7;        // 0..23
          const int d = gn & (HD - 1);
          const unsigned short h = f2bf(fv);
          if (head < 16) {
            o0[(((size_t)(b*NH + head) * TLEN + t) << 7) + d] = (short)h;
          } else if (head < 20) {
            o1[(((size_t)(b*NKV + (head-16)) * TLEN + t) << 7) + d] = (short)h;
          } else {
            o2[(((size_t)(b*NKV + (head-20)) * HD + d) << 11) + t] = (short)h;  // vT[b][kv][d][t]
          }
        }
      }
    }
  }
}

// ---------------------------------------------------------------------------
// RoPE in place; attention scale 1/sqrt(128) folded into q (unchanged R6).
// ---------------------------------------------------------------------------
__global__ __launch_bounds__(256) void rope_kernel(short* __restrict__ qb,
                                                   short* __restrict__ kb)
{
  const int idx = blockIdx.x * 256 + threadIdx.x;   // exactly 80*2048*64 threads
  const int per_plane = TLEN * 64;
  const int plane = idx / per_plane;
  const int rem = idx - plane * per_plane;
  const int t = rem >> 6;
  const int i = rem & 63;
  short* base = (plane < 64) ? (qb + (size_t)plane * (TLEN*HD))
                             : (kb + (size_t)(plane - 64) * (TLEN*HD));
  const size_t off = (size_t)t * HD + 2*i;
  const float x1 = bf2f((unsigned short)base[off]);
  const float x2 = bf2f((unsigned short)base[off+1]);
  const float inv = __expf(-0.14391156847064198f * (float)i);  // 10000^(-2i/128)
  const float ang = (float)t * inv;
  float s, c;
  sincosf(ang, &s, &c);
  const float qscale = (plane < 64) ? 0.08838834764831845f : 1.0f;  // 1/sqrt(128) on q only
  base[off]   = (short)f2bf((x1*c - x2*s) * qscale);
  base[off+1] = (short)f2bf((x1*s + x2*c) * qscale);
}

// ---------------------------------------------------------------------------
// Flash attention (causal), R7: 8-wave blocks + MFMA row-sum.
//  - 512 threads, 128 q-rows/block: same staged K/V tiles feed 8 waves
//    -> 2 blocks/CU x 8 waves = 4 waves/SIMD (2x latency hiding vs R6's 2),
//    and K/V HBM re-fetch halves.
//  - row-sum l = P*ones via 2 extra MFMAs per tile (C-layout replicates the
//    sum across cl; lands in [r] slots) -> deletes the 4x4 shfl sum chain.
//    Denominator now uses the same bf16-quantized P as the numerator.
//  - causal pairing: block handles q-tiles qi and 15-qi -> 34 k-tiles each.
//  - mask on the last 2 k-tiles (diagonal region of the 128-row q-tile).
// R5 staging (coop double-buffered global_load_lds, swizzled) + R6 diet kept.
// ---------------------------------------------------------------------------
__device__ inline void stage_tiles(short* Ks, short* Vs,
                                   const short* Kp, const short* Vp,
                                   int k0, int tid, int wave) {
  // K: 1024 chunks (64 rows x 16), 2 issues x 512 threads
#pragma unroll
  for (int i = 0; i < 2; i++) {
    const int chunk = i*512 + tid;
    const int row = chunk >> 4;
    const int cc  = (chunk & 15) ^ (row & 7);
    gload_lds16(Kp + (size_t)(k0 + row)*HD + cc*8,
                Ks + ((i*512 + wave*64) << 3));
  }
  // V: 1024 chunks (128 rows x 8), 2 issues x 512 threads
#pragma unroll
  for (int i = 0; i < 2; i++) {
    const int chunk = i*512 + tid;
    const int row = chunk >> 3;
    const int cc  = (chunk & 7) ^ (row & 7);
    gload_lds16(Vp + (size_t)row*TLEN + k0 + cc*8,
                Vs + ((i*512 + wave*64) << 3));
  }
}

__global__ __launch_bounds__(512, 4) void attn_kernel(
    const short* __restrict__ qb, const short* __restrict__ kb,
    const short* __restrict__ vtb, short* __restrict__ yb)
{
  __shared__ __align__(16) short Ks[2][64*128];   // 32 KB
  __shared__ __align__(16) short Vs[2][128*64];   // 32 KB
  __shared__ short Plds[8][16][64];               // 16 KB  (80 KB -> 2 blk/CU)
  const int tid  = threadIdx.x;
  const int wave = tid >> 6;       // 0..7
  const int lane = tid & 63;
  const int cl   = lane & 15;
  const int quad = lane >> 4;
  const int bh = blockIdx.y;
  const int b = bh >> 4, h = bh & 15;
  const int kvh = h >> 2;

  const short* Qp = qb  + (size_t)(b*NH  + h)   * TLEN * HD;
  const short* Kp = kb  + (size_t)(b*NKV + kvh) * TLEN * HD;
  const short* Vp = vtb + (size_t)(b*NKV + kvh) * HD * TLEN;
  short* Pw = &Plds[wave][0][0];
  const int swz = (cl & 7) << 3;   // read-side chunk XOR, in shorts

  bf16x8 ones;
#pragma unroll
  for (int i = 0; i < 8; i++) ones[i] = (short)0x3F80;  // bf16 1.0

#pragma unroll 1
  for (int pass = 0; pass < 2; ++pass) {
    const int qi = pass ? (TLEN/128 - 1 - (int)blockIdx.x) : (int)blockIdx.x;
    const int q0 = qi * 128;
    const int ntiles = 2*qi + 2;

    bf16x8 qf[4];
    const int qrow = q0 + wave*16 + cl;
#pragma unroll
    for (int s = 0; s < 4; s++)
      qf[s] = *(const bf16x8*)(Qp + (size_t)qrow*HD + s*32 + quad*8);

    f32x4 O[8];
#pragma unroll
    for (int d = 0; d < 8; d++) O[d] = (f32x4){0.f, 0.f, 0.f, 0.f};
    f32x4 Ol = (f32x4){0.f, 0.f, 0.f, 0.f};        // row sums via MFMA
    float m_i[4];
#pragma unroll
    for (int r = 0; r < 4; r++) m_i[r] = -1e9f;

    // prologue: stage tile 0
    stage_tiles(Ks[0], Vs[0], Kp, Vp, 0, tid, wave);
    __syncthreads();
    int cur = 0;

    for (int kt = 0; kt < ntiles; kt++) {
      const int k0 = kt * 64;

      // prefetch next tile into the other buffer (DMA flies under compute)
      if (kt + 1 < ntiles)
        stage_tiles(Ks[cur^1], Vs[cur^1], Kp, Vp, k0 + 64, tid, wave);

      const short* Kt = Ks[cur];
      const short* Vt = Vs[cur];

      // --- QK^T from LDS (q pre-scaled by 1/sqrt(128)) ---
      f32x4 S[4];
#pragma unroll
      for (int j = 0; j < 4; j++) S[j] = (f32x4){0.f, 0.f, 0.f, 0.f};
#pragma unroll
      for (int s = 0; s < 4; s++) {
        bf16x8 kfj[4];
#pragma unroll
        for (int j = 0; j < 4; j++)
          kfj[j] = *(const bf16x8*)(&Kt[(size_t)(j*16 + cl)*128 + ((((s*4 + quad) << 3) ^ swz))]);
#pragma unroll
        for (int j = 0; j < 4; j++)
          S[j] = __builtin_amdgcn_mfma_f32_16x16x32_bf16(qf[s], kfj[j], S[j], 0, 0, 0);
      }

      // --- causal mask: only the 2 diagonal-region tiles need it ---
      if (kt >= ntiles - 2) {
#pragma unroll
        for (int j = 0; j < 4; j++) {
          const int col = k0 + j*16 + cl;
#pragma unroll
          for (int r = 0; r < 4; r++) {
            const int row = q0 + wave*16 + quad*4 + r;
            if (col > row) S[j][r] = -1e9f;
          }
        }
      }

      // --- row max (shfl chain; sum chain is gone — MFMA ones-trick) ---
      float pmax[4];
#pragma unroll
      for (int r = 0; r < 4; r++) {
        float mx = fmaxf(fmaxf(S[0][r], S[1][r]), fmaxf(S[2][r], S[3][r]));
#pragma unroll
        for (int off = 1; off < 16; off <<= 1) mx = fmaxf(mx, __shfl_xor(mx, off));
        pmax[r] = mx;
      }
      // --- defer-max (T13, THR=8) ---
      const int ok = (pmax[0] - m_i[0] <= 8.f) && (pmax[1] - m_i[1] <= 8.f) &&
                     (pmax[2] - m_i[2] <= 8.f) && (pmax[3] - m_i[3] <= 8.f);
      if (!__all(ok)) {
#pragma unroll
        for (int r = 0; r < 4; r++) {
          const float mnew = fmaxf(m_i[r], pmax[r]);
          const float alpha = __expf(m_i[r] - mnew);
          Ol[r] *= alpha;
          m_i[r] = mnew;
#pragma unroll
          for (int d = 0; d < 8; d++) O[d][r] *= alpha;
        }
      }
      // --- P = exp(S - m) ---
#pragma unroll
      for (int r = 0; r < 4; r++)
#pragma unroll
        for (int j = 0; j < 4; j++)
          S[j][r] = __expf(S[j][r] - m_i[r]);

      // --- P -> LDS (wave-private, XOR-swizzled; no barrier needed) ---
#pragma unroll
      for (int j = 0; j < 4; j++)
#pragma unroll
        for (int r = 0; r < 4; r++) {
          const int row = quad*4 + r;
          int idx = row*64 + j*16 + cl;
          idx ^= (row & 7) << 3;
          Pw[idx] = (short)f2bf(S[j][r]);
        }

      // --- PV + row-sum: P from LDS (A-operand), V from LDS tile ---
#pragma unroll
      for (int s2 = 0; s2 < 2; s2++) {
        int idx = cl*64 + s2*32 + quad*8;
        idx ^= (cl & 7) << 3;
        bf16x8 pf = *(const bf16x8*)(&Pw[idx]);
        Ol = __builtin_amdgcn_mfma_f32_16x16x32_bf16(pf, ones, Ol, 0, 0, 0);
#pragma unroll
        for (int d = 0; d < 8; d++) {
          bf16x8 vfd = *(const bf16x8*)(&Vt[(size_t)(d*16 + cl)*64 + ((((s2*4 + quad) << 3) ^ swz))]);
          O[d] = __builtin_amdgcn_mfma_f32_16x16x32_bf16(pf, vfd, O[d], 0, 0, 0);
        }
      }

      __syncthreads();   // all waves done with buf[cur]; prefetch drained
      cur ^= 1;
    }

    float linv[4];
#pragma unroll
    for (int r = 0; r < 4; r++) linv[r] = 1.0f / Ol[r];
#pragma unroll
    for (int d = 0; d < 8; d++) {
#pragma unroll
      for (int r = 0; r < 4; r++) {
        const int t = q0 + wave*16 + quad*4 + r;
        yb[(size_t)(b*TLEN + t) * CDIM + h*HD + d*16 + cl] = (short)f2bf(O[d][r] * linv[r]);
      }
    }
  }
}

// ---------------------------------------------------------------------------
// Memory plan (81 MB workspace peak, same as R4-R6 passing):
//   ws:   flag @ 0
//         qb  @  1MB (32MB)  q  [B,16,T,128] bf16
//         kb  @ 33MB ( 8MB)  k  [B,4,T,128]  bf16  -> wpb after attn (k dead)
//         vtb @ 41MB ( 8MB)  vT [B,4,128,T]  bf16
//         yb  @ 49MB (32MB)  y  [B,T,C]      bf16
//   d_out (64MB fp32, write-only until gemm1) doubles as scratch:
//         xb  @ d_out+0    (32MB) x bf16      — dead after gemm0
//         wab @ d_out+32MB (12MB) w_attn bf16 — dead after gemm0
// ---------------------------------------------------------------------------
extern "C" void kernel_launch(void* const* d_in, const int* in_sizes, int n_in,
                              void* d_out, int out_size, void* d_ws, size_t ws_size,
                              hipStream_t stream)
{
  const void* x      = d_in[0];   // [B,T,C]
  const void* w_attn = d_in[1];   // [3072,2048]
  const void* w_proj = d_in[2];   // [2048,2048]

  char* ws = (char*)d_ws;
  int*   flag = (int*)ws;
  short* qb  = (short*)(ws + (size_t) 1*1024*1024);
  short* kb  = (short*)(ws + (size_t)33*1024*1024);
  short* vtb = (short*)(ws + (size_t)41*1024*1024);
  short* yb  = (short*)(ws + (size_t)49*1024*1024);
  short* xb  = (short*)d_out;                              // scratch in output buf
  short* wab = (short*)((char*)d_out + (size_t)32*1024*1024);
  short* wpb = kb;                                         // alias: k dead after attn

  dim3 blk(256);
  detect_kernel<<<1, blk, 0, stream>>>(w_proj, flag);
  cvt_kernel<<<dim3((MROWS*CDIM/8)/256), blk, 0, stream>>>(x, xb, MROWS*CDIM/8, flag);
  cvt_kernel<<<dim3((3072*CDIM/8)/256), blk, 0, stream>>>(w_attn, wab, 3072*CDIM/8, flag);
  gemm_bt<0><<<dim3(3072/128, MROWS/128), blk, 0, stream>>>(xb, wab, qb, kb, vtb, nullptr, flag);
  rope_kernel<<<dim3((80*TLEN*64)/256), blk, 0, stream>>>(qb, kb);
  attn_kernel<<<dim3(TLEN/256, BSZ*NH), dim3(512), 0, stream>>>(qb, kb, vtb, yb);
  cvt_kernel<<<dim3((CDIM*CDIM/8)/256), blk, 0, stream>>>(w_proj, wpb, CDIM*CDIM/8, flag);
  gemm_bt<1><<<dim3(CDIM/128, MROWS/128), blk, 0, stream>>>(yb, wpb, (short*)d_out,
                                                            nullptr, nullptr, (float*)d_out, flag);
}

// Round 8
// 507.870 us; speedup vs baseline: 2.8983x; 1.0903x over previous
//
#include <hip/hip_runtime.h>
#include <math.h>

#define NH   16
#define NKV  4
#define HD   128
#define BSZ  4
#define TLEN 2048
#define CDIM 2048
#define MROWS (BSZ*TLEN)   // 8192

typedef short bf16x8 __attribute__((ext_vector_type(8)));
typedef float f32x4  __attribute__((ext_vector_type(4)));
typedef int   int4v  __attribute__((ext_vector_type(4)));

__device__ inline float bf2f(unsigned short h) {
  union { unsigned u; float f; } x; x.u = ((unsigned)h) << 16; return x.f;
}
__device__ inline unsigned short f2bf(float f) {
  union { float f; unsigned u; } x; x.f = f;
  unsigned u = x.u;
  return (unsigned short)((u + 0x7FFFu + ((u >> 16) & 1u)) >> 16);
}

// Async global->LDS DMA, 16B per lane. LDS dest = wave-uniform base + lane*16.
__device__ inline void gload_lds16(const void* g, void* l) {
  __builtin_amdgcn_global_load_lds((const __attribute__((address_space(1))) void*)g,
                                   (__attribute__((address_space(3))) void*)l, 16, 0, 0);
}

// ---------------------------------------------------------------------------
// Dtype detector (unchanged): flag=1 => inputs are packed bf16.
// ---------------------------------------------------------------------------
__global__ void detect_kernel(const void* __restrict__ wproj, int* __restrict__ flag) {
  __shared__ int cnt;
  if (threadIdx.x == 0) cnt = 0;
  __syncthreads();
  const unsigned short* s = (const unsigned short*)wproj;
  unsigned short v = s[2 * threadIdx.x];          // 256 even shorts
  int e = (v >> 7) & 0xFF;
  if (e >= 90 && e <= 141) atomicAdd(&cnt, 1);
  __syncthreads();
  if (threadIdx.x == 0) *flag = (cnt >= 192) ? 1 : 0;
}

// Produce 8 contiguous bf16 from source (bf16 copy or fp32 convert).
__device__ inline void stage8(short* dst, const void* src, size_t eoff, int isbf) {
  if (isbf) {
    *(int4v*)dst = *(const int4v*)((const short*)src + eoff);
  } else {
    const f32x4* f = (const f32x4*)((const float*)src + eoff);
    f32x4 a = f[0], b = f[1];
    __align__(16) short t[8];
    t[0] = (short)f2bf(a[0]); t[1] = (short)f2bf(a[1]);
    t[2] = (short)f2bf(a[2]); t[3] = (short)f2bf(a[3]);
    t[4] = (short)f2bf(b[0]); t[5] = (short)f2bf(b[1]);
    t[6] = (short)f2bf(b[2]); t[7] = (short)f2bf(b[3]);
    *(int4v*)dst = *(int4v*)t;
  }
}

// ---------------------------------------------------------------------------
// One-shot convert/copy to packed bf16. 8 elems/thread, fully coalesced.
// ---------------------------------------------------------------------------
__global__ __launch_bounds__(256) void cvt_kernel(const void* __restrict__ src,
                                                  short* __restrict__ dst,
                                                  int n8, const int* __restrict__ flagp)
{
  const int fl = *flagp;
  const int i = blockIdx.x * 256 + threadIdx.x;
  if (i >= n8) return;
  __align__(16) short t[8];
  stage8(t, src, (size_t)i * 8, fl);
  *(int4v*)(dst + (size_t)i * 8) = *(int4v*)t;
}

// ---------------------------------------------------------------------------
// GEMM  C[m,n] = sum_k A[m,k] * W[n,k]   (bf16 inputs, fp32 accum)
// R8: 256x256 tile, BK=32, 8 waves (2Mx4N, each 128x64 out), quad-buffered
// LDS (4 x 32KB = 128KB) with prefetch depth 3 and COUNTED vmcnt(8) per tile
// (T3+T4: loads are issued 3 tiles ahead and never drained to 0 in the loop;
// m218: counted-vs-drain0 = +38-73%). Raw s_barrier once per tile bounds wave
// drift to 1 iter; reads of buf[kt&3] never collide with DMA into buf[(kt+3)&3].
//
// LDS tile layout (per matrix, 256 rows x 32 k): packed row-pairs [128][64]:
//   lr = row>>1, chunk c = (row&1)*4 + k/8, stored at chunk' = c ^ (lr&7).
// Stage (inverse-swizzled global src, linear DMA dest — rule 21) and read use
// the same involution; read pattern = 2 lanes per bank-group (free, m136).
// Bijection hand-verified: chunk 9 -> (row2,qk0) -> read row2/quad0 @ short 72.
// ---------------------------------------------------------------------------
template<int MODE>
__global__ __launch_bounds__(512, 2) void gemm_bt(
    const short* __restrict__ A, const short* __restrict__ W,
    short* __restrict__ o0, short* __restrict__ o1, short* __restrict__ o2,
    float* __restrict__ o0f, const int* __restrict__ flagp)
{
  __shared__ __align__(16) short SB[4][16384];   // 128 KB: [buf][ A:0..8191 | B:8192..16383 ]
  const int fl = *flagp;
  const int tid  = threadIdx.x;
  const int wave = tid >> 6;        // 0..7
  const int lane = tid & 63;
  const int cl   = lane & 15;
  const int quad = lane >> 4;
  const int wm = wave >> 2;         // 0..1  (M half)
  const int wn = wave & 3;          // 0..3  (N quarter)
  // bijective XCD swizzle (grids 384 / 256 blocks, both %8==0)
  const int nwgx = gridDim.x;
  int wg = (int)blockIdx.y * nwgx + (int)blockIdx.x;
  const int cpx = (nwgx * (int)gridDim.y) >> 3;
  wg = (wg & 7) * cpx + (wg >> 3);
  const int m0 = (wg / nwgx) * 256;
  const int n0 = (wg % nwgx) * 256;

  // per-thread-constant fragment read addresses (shorts):
  //   lr&7 == cl>>1 for every fragment row; c = ((cl&1)<<2 | quad) ^ (cl>>1)
  const int cswz  = (((cl & 1) << 2) | quad) ^ (cl >> 1);
  const int abase = (wm*64 + (cl >> 1)) * 64 + cswz * 8;           // + i*512
  const int bbase = 8192 + (wn*32 + (cl >> 1)) * 64 + cswz * 8;    // + j*512

  f32x4 acc[8][4];
#pragma unroll
  for (int i = 0; i < 8; i++)
#pragma unroll
    for (int j = 0; j < 4; j++) acc[i][j] = (f32x4){0.f, 0.f, 0.f, 0.f};

  const short* Asrc = A + (size_t)m0 * CDIM;
  const short* Wsrc = W + (size_t)n0 * CDIM;

  // stage one 256x32 tile (matrix at src, k-offset kk bf16) into dst (linear DMA)
  auto stage1 = [&](const short* src, int kk, short* dst) {
#pragma unroll
    for (int i = 0; i < 2; i++) {
      const int chunk = i*512 + tid;          // 0..1023
      const int lr  = chunk >> 3;
      const int c   = (chunk & 7) ^ (lr & 7); // inverse swizzle on SOURCE
      const int row = lr*2 + (c >> 2);
      gload_lds16(src + (size_t)row * CDIM + kk + (c & 3)*8,
                  dst + ((i*512 + wave*64) << 3));
    }
  };
#define STAGE(t) { short* db = &SB[(t)&3][0]; stage1(Asrc, (t)*32, db); stage1(Wsrc, (t)*32, db + 8192); }

  STAGE(0); STAGE(1); STAGE(2);               // 12 per-wave loads in flight
  const int nt = CDIM / 32;                   // 64 K-tiles
  for (int kt = 0; kt < nt; ++kt) {
    const int rem = nt - kt;                  // tiles not yet consumed (incl. kt)
    if (rem > 2)       asm volatile("s_waitcnt vmcnt(8)" : : : "memory");
    else if (rem == 2) asm volatile("s_waitcnt vmcnt(4)" : : : "memory");
    else               asm volatile("s_waitcnt vmcnt(0)" : : : "memory");
    __builtin_amdgcn_s_barrier();             // all waves: tile kt landed, kt-1 reads done
    if (kt + 3 < nt) STAGE(kt+3);             // refill depth-3 pipeline
    const short* Tb = &SB[kt & 3][0];
    bf16x8 af[8], bfj[4];
#pragma unroll
    for (int i = 0; i < 8; i++) af[i]  = *(const bf16x8*)&Tb[abase + i*512];
#pragma unroll
    for (int j = 0; j < 4; j++) bfj[j] = *(const bf16x8*)&Tb[bbase + j*512];
    __builtin_amdgcn_s_setprio(1);
#pragma unroll
    for (int i = 0; i < 8; i++)
#pragma unroll
      for (int j = 0; j < 4; j++)
        acc[i][j] = __builtin_amdgcn_mfma_f32_16x16x32_bf16(af[i], bfj[j], acc[i][j], 0, 0, 0);
    __builtin_amdgcn_s_setprio(0);
  }
#undef STAGE

  // C/D layout (verified m89/m91): col = lane&15, row = quad*4 + reg.
#pragma unroll
  for (int i = 0; i < 8; i++) {
#pragma unroll
    for (int j = 0; j < 4; j++) {
#pragma unroll
      for (int r = 0; r < 4; r++) {
        const int gm = m0 + wm*128 + i*16 + quad*4 + r;
        const int gn = n0 + wn*64  + j*16 + cl;
        const float fv = acc[i][j][r];
        if (MODE == 1) {
          if (fl) o0[(size_t)gm * CDIM + gn] = (short)f2bf(fv);
          else    o0f[(size_t)gm * CDIM + gn] = fv;
        } else {
          const int b = gm >> 11;          // /TLEN
          const int t = gm & (TLEN - 1);
          const int head = gn >> 7;        // 0..23
          const int d = gn & (HD - 1);
          const unsigned short h = f2bf(fv);
          if (head < 16) {
            o0[(((size_t)(b*NH + head) * TLEN + t) << 7) + d] = (short)h;
          } else if (head < 20) {
            o1[(((size_t)(b*NKV + (head-16)) * TLEN + t) << 7) + d] = (short)h;
          } else {
            o2[(((size_t)(b*NKV + (head-20)) * HD + d) << 11) + t] = (short)h;  // vT[b][kv][d][t]
          }
        }
      }
    }
  }
}

// ---------------------------------------------------------------------------
// RoPE in place; attention scale 1/sqrt(128) folded into q (unchanged R6).
// ---------------------------------------------------------------------------
__global__ __launch_bounds__(256) void rope_kernel(short* __restrict__ qb,
                                                   short* __restrict__ kb)
{
  const int idx = blockIdx.x * 256 + threadIdx.x;   // exactly 80*2048*64 threads
  const int per_plane = TLEN * 64;
  const int plane = idx / per_plane;
  const int rem = idx - plane * per_plane;
  const int t = rem >> 6;
  const int i = rem & 63;
  short* base = (plane < 64) ? (qb + (size_t)plane * (TLEN*HD))
                             : (kb + (size_t)(plane - 64) * (TLEN*HD));
  const size_t off = (size_t)t * HD + 2*i;
  const float x1 = bf2f((unsigned short)base[off]);
  const float x2 = bf2f((unsigned short)base[off+1]);
  const float inv = __expf(-0.14391156847064198f * (float)i);  // 10000^(-2i/128)
  const float ang = (float)t * inv;
  float s, c;
  sincosf(ang, &s, &c);
  const float qscale = (plane < 64) ? 0.08838834764831845f : 1.0f;  // 1/sqrt(128) on q only
  base[off]   = (short)f2bf((x1*c - x2*s) * qscale);
  base[off+1] = (short)f2bf((x1*s + x2*c) * qscale);
}

// ---------------------------------------------------------------------------
// Flash attention (causal) — unchanged R7 (8-wave, MFMA row-sum, defer-max,
// coop double-buffered gload_lds staging; measured: dropped out of top-5).
// ---------------------------------------------------------------------------
__device__ inline void stage_tiles(short* Ks, short* Vs,
                                   const short* Kp, const short* Vp,
                                   int k0, int tid, int wave) {
#pragma unroll
  for (int i = 0; i < 2; i++) {
    const int chunk = i*512 + tid;
    const int row = chunk >> 4;
    const int cc  = (chunk & 15) ^ (row & 7);
    gload_lds16(Kp + (size_t)(k0 + row)*HD + cc*8,
                Ks + ((i*512 + wave*64) << 3));
  }
#pragma unroll
  for (int i = 0; i < 2; i++) {
    const int chunk = i*512 + tid;
    const int row = chunk >> 3;
    const int cc  = (chunk & 7) ^ (row & 7);
    gload_lds16(Vp + (size_t)row*TLEN + k0 + cc*8,
                Vs + ((i*512 + wave*64) << 3));
  }
}

__global__ __launch_bounds__(512, 4) void attn_kernel(
    const short* __restrict__ qb, const short* __restrict__ kb,
    const short* __restrict__ vtb, short* __restrict__ yb)
{
  __shared__ __align__(16) short Ks[2][64*128];   // 32 KB
  __shared__ __align__(16) short Vs[2][128*64];   // 32 KB
  __shared__ short Plds[8][16][64];               // 16 KB  (80 KB -> 2 blk/CU)
  const int tid  = threadIdx.x;
  const int wave = tid >> 6;       // 0..7
  const int lane = tid & 63;
  const int cl   = lane & 15;
  const int quad = lane >> 4;
  const int bh = blockIdx.y;
  const int b = bh >> 4, h = bh & 15;
  const int kvh = h >> 2;

  const short* Qp = qb  + (size_t)(b*NH  + h)   * TLEN * HD;
  const short* Kp = kb  + (size_t)(b*NKV + kvh) * TLEN * HD;
  const short* Vp = vtb + (size_t)(b*NKV + kvh) * HD * TLEN;
  short* Pw = &Plds[wave][0][0];
  const int swz = (cl & 7) << 3;   // read-side chunk XOR, in shorts

  bf16x8 ones;
#pragma unroll
  for (int i = 0; i < 8; i++) ones[i] = (short)0x3F80;  // bf16 1.0

#pragma unroll 1
  for (int pass = 0; pass < 2; ++pass) {
    const int qi = pass ? (TLEN/128 - 1 - (int)blockIdx.x) : (int)blockIdx.x;
    const int q0 = qi * 128;
    const int ntiles = 2*qi + 2;

    bf16x8 qf[4];
    const int qrow = q0 + wave*16 + cl;
#pragma unroll
    for (int s = 0; s < 4; s++)
      qf[s] = *(const bf16x8*)(Qp + (size_t)qrow*HD + s*32 + quad*8);

    f32x4 O[8];
#pragma unroll
    for (int d = 0; d < 8; d++) O[d] = (f32x4){0.f, 0.f, 0.f, 0.f};
    f32x4 Ol = (f32x4){0.f, 0.f, 0.f, 0.f};        // row sums via MFMA
    float m_i[4];
#pragma unroll
    for (int r = 0; r < 4; r++) m_i[r] = -1e9f;

    stage_tiles(Ks[0], Vs[0], Kp, Vp, 0, tid, wave);
    __syncthreads();
    int cur = 0;

    for (int kt = 0; kt < ntiles; kt++) {
      const int k0 = kt * 64;

      if (kt + 1 < ntiles)
        stage_tiles(Ks[cur^1], Vs[cur^1], Kp, Vp, k0 + 64, tid, wave);

      const short* Kt = Ks[cur];
      const short* Vt = Vs[cur];

      f32x4 S[4];
#pragma unroll
      for (int j = 0; j < 4; j++) S[j] = (f32x4){0.f, 0.f, 0.f, 0.f};
#pragma unroll
      for (int s = 0; s < 4; s++) {
        bf16x8 kfj[4];
#pragma unroll
        for (int j = 0; j < 4; j++)
          kfj[j] = *(const bf16x8*)(&Kt[(size_t)(j*16 + cl)*128 + ((((s*4 + quad) << 3) ^ swz))]);
#pragma unroll
        for (int j = 0; j < 4; j++)
          S[j] = __builtin_amdgcn_mfma_f32_16x16x32_bf16(qf[s], kfj[j], S[j], 0, 0, 0);
      }

      if (kt >= ntiles - 2) {
#pragma unroll
        for (int j = 0; j < 4; j++) {
          const int col = k0 + j*16 + cl;
#pragma unroll
          for (int r = 0; r < 4; r++) {
            const int row = q0 + wave*16 + quad*4 + r;
            if (col > row) S[j][r] = -1e9f;
          }
        }
      }

      float pmax[4];
#pragma unroll
      for (int r = 0; r < 4; r++) {
        float mx = fmaxf(fmaxf(S[0][r], S[1][r]), fmaxf(S[2][r], S[3][r]));
#pragma unroll
        for (int off = 1; off < 16; off <<= 1) mx = fmaxf(mx, __shfl_xor(mx, off));
        pmax[r] = mx;
      }
      const int ok = (pmax[0] - m_i[0] <= 8.f) && (pmax[1] - m_i[1] <= 8.f) &&
                     (pmax[2] - m_i[2] <= 8.f) && (pmax[3] - m_i[3] <= 8.f);
      if (!__all(ok)) {
#pragma unroll
        for (int r = 0; r < 4; r++) {
          const float mnew = fmaxf(m_i[r], pmax[r]);
          const float alpha = __expf(m_i[r] - mnew);
          Ol[r] *= alpha;
          m_i[r] = mnew;
#pragma unroll
          for (int d = 0; d < 8; d++) O[d][r] *= alpha;
        }
      }
#pragma unroll
      for (int r = 0; r < 4; r++)
#pragma unroll
        for (int j = 0; j < 4; j++)
          S[j][r] = __expf(S[j][r] - m_i[r]);

#pragma unroll
      for (int j = 0; j < 4; j++)
#pragma unroll
        for (int r = 0; r < 4; r++) {
          const int row = quad*4 + r;
          int idx = row*64 + j*16 + cl;
          idx ^= (row & 7) << 3;
          Pw[idx] = (short)f2bf(S[j][r]);
        }

#pragma unroll
      for (int s2 = 0; s2 < 2; s2++) {
        int idx = cl*64 + s2*32 + quad*8;
        idx ^= (cl & 7) << 3;
        bf16x8 pf = *(const bf16x8*)(&Pw[idx]);
        Ol = __builtin_amdgcn_mfma_f32_16x16x32_bf16(pf, ones, Ol, 0, 0, 0);
#pragma unroll
        for (int d = 0; d < 8; d++) {
          bf16x8 vfd = *(const bf16x8*)(&Vt[(size_t)(d*16 + cl)*64 + ((((s2*4 + quad) << 3) ^ swz))]);
          O[d] = __builtin_amdgcn_mfma_f32_16x16x32_bf16(pf, vfd, O[d], 0, 0, 0);
        }
      }

      __syncthreads();
      cur ^= 1;
    }

    float linv[4];
#pragma unroll
    for (int r = 0; r < 4; r++) linv[r] = 1.0f / Ol[r];
#pragma unroll
    for (int d = 0; d < 8; d++) {
#pragma unroll
      for (int r = 0; r < 4; r++) {
        const int t = q0 + wave*16 + quad*4 + r;
        yb[(size_t)(b*TLEN + t) * CDIM + h*HD + d*16 + cl] = (short)f2bf(O[d][r] * linv[r]);
      }
    }
  }
}

// ---------------------------------------------------------------------------
// Memory plan (81 MB workspace peak, same as R4-R7 passing):
//   ws:   flag @ 0
//         qb  @  1MB (32MB)  q  [B,16,T,128] bf16
//         kb  @ 33MB ( 8MB)  k  [B,4,T,128]  bf16  -> wpb after attn (k dead)
//         vtb @ 41MB ( 8MB)  vT [B,4,128,T]  bf16
//         yb  @ 49MB (32MB)  y  [B,T,C]      bf16
//   d_out (64MB fp32, write-only until gemm1) doubles as scratch:
//         xb  @ d_out+0    (32MB) x bf16      — dead after gemm0
//         wab @ d_out+32MB (12MB) w_attn bf16 — dead after gemm0
// ---------------------------------------------------------------------------
extern "C" void kernel_launch(void* const* d_in, const int* in_sizes, int n_in,
                              void* d_out, int out_size, void* d_ws, size_t ws_size,
                              hipStream_t stream)
{
  const void* x      = d_in[0];   // [B,T,C]
  const void* w_attn = d_in[1];   // [3072,2048]
  const void* w_proj = d_in[2];   // [2048,2048]

  char* ws = (char*)d_ws;
  int*   flag = (int*)ws;
  short* qb  = (short*)(ws + (size_t) 1*1024*1024);
  short* kb  = (short*)(ws + (size_t)33*1024*1024);
  short* vtb = (short*)(ws + (size_t)41*1024*1024);
  short* yb  = (short*)(ws + (size_t)49*1024*1024);
  short* xb  = (short*)d_out;                              // scratch in output buf
  short* wab = (short*)((char*)d_out + (size_t)32*1024*1024);
  short* wpb = kb;                                         // alias: k dead after attn

  dim3 blk(256);
  detect_kernel<<<1, blk, 0, stream>>>(w_proj, flag);
  cvt_kernel<<<dim3((MROWS*CDIM/8)/256), blk, 0, stream>>>(x, xb, MROWS*CDIM/8, flag);
  cvt_kernel<<<dim3((3072*CDIM/8)/256), blk, 0, stream>>>(w_attn, wab, 3072*CDIM/8, flag);
  gemm_bt<0><<<dim3(3072/256, MROWS/256), dim3(512), 0, stream>>>(xb, wab, qb, kb, vtb, nullptr, flag);
  rope_kernel<<<dim3((80*TLEN*64)/256), blk, 0, stream>>>(qb, kb);
  attn_kernel<<<dim3(TLEN/256, BSZ*NH), dim3(512), 0, stream>>>(qb, kb, vtb, yb);
  cvt_kernel<<<dim3((CDIM*CDIM/8)/256), blk, 0, stream>>>(w_proj, wpb, CDIM*CDIM/8, flag);
  gemm_bt<1><<<dim3(CDIM/256, MROWS/256), dim3(512), 0, stream>>>(yb, wpb, (short*)d_out,
                                                                  nullptr, nullptr, (float*)d_out, flag);
}